// Round 2
// baseline (717.301 us; speedup 1.0000x reference)
//
#include <hip/hip_runtime.h>

#define N_NODES 50000
#define N_EDGES 800000
#define N_GRAPHS 256
#define HID 128
#define OUT_CH 10
#define BN_EPS 1e-5f

// ---------------- workspace layout (4-byte element offsets) ----------------
#define OFF_H       0            // 6,400,000 f32
#define OFF_AGG     6400000      // 6,400,000 f32
#define OFF_DEG     12800000     // 50,000 i32
#define OFF_ROWPTR  12850000     // 50,001 i32
#define OFF_CURSOR  12900004     // 50,000 i32
#define OFF_CSR     12950004     // 800,000 i32
#define OFF_DINV    13750004     // 50,000 f32
#define OFF_BNST    13800004     // 3*256 f32 (sum[128], sumsq[128] per layer)
#define OFF_BNCOEF  13800772     // 256 f32 (scale[128], shift[128])
#define OFF_POOL    13801028     // 256*128 f32
#define OFF_CNT     13833796     // 256 f32
#define OFF_BSUM    13834052     // 256 i32

// ---------------- init: zero the accumulated regions ----------------
__global__ void k_init(int* deg, float* bnst, float* pool, float* cnt) {
    int i = blockIdx.x * 256 + threadIdx.x;
    if (i < N_NODES) deg[i] = 0;
    if (i < 768) bnst[i] = 0.f;
    if (i < N_GRAPHS * HID) pool[i] = 0.f;
    if (i < N_GRAPHS) cnt[i] = 0.f;
}

// ---------------- degree count (by dst) ----------------
__global__ void k_deg(const int* __restrict__ ei, int* __restrict__ deg) {
    int i = blockIdx.x * 256 + threadIdx.x;
    if (i < N_EDGES) atomicAdd(&deg[ei[N_EDGES + i]], 1);
}

// ---------------- 3-kernel exclusive scan over deg[50000] ----------------
__global__ void k_s1(const int* __restrict__ deg, int* __restrict__ bsum) {
    __shared__ int sh[256];
    int i = blockIdx.x * 256 + threadIdx.x;
    sh[threadIdx.x] = (i < N_NODES) ? deg[i] : 0;
    __syncthreads();
    for (int o = 128; o > 0; o >>= 1) {
        if (threadIdx.x < o) sh[threadIdx.x] += sh[threadIdx.x + o];
        __syncthreads();
    }
    if (threadIdx.x == 0) bsum[blockIdx.x] = sh[0];
}

__global__ void k_s2(int* __restrict__ bsum, int nb) {
    __shared__ int sh[256];
    int t = threadIdx.x;
    int v = (t < nb) ? bsum[t] : 0;
    sh[t] = v;
    __syncthreads();
    for (int o = 1; o < 256; o <<= 1) {
        int x = (t >= o) ? sh[t - o] : 0;
        __syncthreads();
        sh[t] += x;
        __syncthreads();
    }
    if (t < nb) bsum[t] = sh[t] - v;  // exclusive
}

__global__ void k_s3(const int* __restrict__ deg, const int* __restrict__ bsum,
                     int* __restrict__ rowptr, int* __restrict__ cursor) {
    __shared__ int sh[256];
    int t = threadIdx.x;
    int i = blockIdx.x * 256 + t;
    int v = (i < N_NODES) ? deg[i] : 0;
    sh[t] = v;
    __syncthreads();
    for (int o = 1; o < 256; o <<= 1) {
        int x = (t >= o) ? sh[t - o] : 0;
        __syncthreads();
        sh[t] += x;
        __syncthreads();
    }
    int ex = bsum[blockIdx.x] + sh[t] - v;
    if (i < N_NODES) {
        rowptr[i] = ex;
        cursor[i] = ex;
        if (i == N_NODES - 1) rowptr[N_NODES] = ex + v;
    }
}

// ---------------- scatter edges into CSR (by dst) ----------------
__global__ void k_scatter(const int* __restrict__ ei, int* __restrict__ cursor,
                          int* __restrict__ csr) {
    int i = blockIdx.x * 256 + threadIdx.x;
    if (i < N_EDGES) {
        int s = ei[i];
        int d = ei[N_EDGES + i];
        int pos = atomicAdd(&cursor[d], 1);
        csr[pos] = s;
    }
}

// ---------------- dinv = rsqrt(in_deg + 1) ----------------
__global__ void k_dinv(const int* __restrict__ deg, float* __restrict__ dinv) {
    int i = blockIdx.x * 256 + threadIdx.x;
    if (i < N_NODES) dinv[i] = rsqrtf((float)(deg[i] + 1));
}

// ---------------- GEMM: H[n,128] = X[n,128] @ W[128,128] ----------------
// block 256 thr; tile 64 rows x 128 cols; K chunks of 32 staged in LDS;
// per-thread micro-tile 4 rows (stride 16) x 8 cols.
__global__ __launch_bounds__(256) void k_gemm(const float* __restrict__ X,
                                              const float* __restrict__ W,
                                              float* __restrict__ H, int nrows) {
    __shared__ float Xs[64][36];    // +4 pad, keeps float4 LDS writes aligned
    __shared__ float Ws[32][128];
    int t = threadIdx.x;
    int tx = t & 15;   // col group: cols tx*8 .. +8
    int ty = t >> 4;   // row group: rows ty + {0,16,32,48}
    int row0 = blockIdx.x * 64;

    float acc[4][8];
#pragma unroll
    for (int i = 0; i < 4; i++)
#pragma unroll
        for (int j = 0; j < 8; j++) acc[i][j] = 0.f;

    for (int k0 = 0; k0 < 128; k0 += 32) {
        // stage X tile: 64x32 = 512 float4; 2 per thread
#pragma unroll
        for (int p = 0; p < 2; p++) {
            int l = t + 256 * p;
            int r = l >> 3, ko = (l & 7) << 2;
            int gr = row0 + r;
            float4 v = make_float4(0.f, 0.f, 0.f, 0.f);
            if (gr < nrows) v = *(const float4*)(X + (long)gr * 128 + k0 + ko);
            *(float4*)(&Xs[r][ko]) = v;
        }
        // stage W chunk: 32x128 = 1024 float4; 4 per thread
#pragma unroll
        for (int p = 0; p < 4; p++) {
            int l = t + 256 * p;
            int kk = l >> 5, off = (l & 31) << 2;
            *(float4*)(&Ws[kk][off]) = *(const float4*)(W + (long)(k0 + kk) * 128 + off);
        }
        __syncthreads();
#pragma unroll
        for (int k = 0; k < 32; k++) {
            float a[4];
            a[0] = Xs[ty][k];
            a[1] = Xs[ty + 16][k];
            a[2] = Xs[ty + 32][k];
            a[3] = Xs[ty + 48][k];
            float4 b0 = *(float4*)(&Ws[k][tx * 8]);
            float4 b1 = *(float4*)(&Ws[k][tx * 8 + 4]);
            float b[8] = {b0.x, b0.y, b0.z, b0.w, b1.x, b1.y, b1.z, b1.w};
#pragma unroll
            for (int i = 0; i < 4; i++)
#pragma unroll
                for (int j = 0; j < 8; j++) acc[i][j] += a[i] * b[j];
        }
        __syncthreads();
    }
#pragma unroll
    for (int i = 0; i < 4; i++) {
        int gr = row0 + ty + 16 * i;
        if (gr < nrows) {
            float4 o0 = make_float4(acc[i][0], acc[i][1], acc[i][2], acc[i][3]);
            float4 o1 = make_float4(acc[i][4], acc[i][5], acc[i][6], acc[i][7]);
            *(float4*)(H + (long)gr * 128 + tx * 8) = o0;
            *(float4*)(H + (long)gr * 128 + tx * 8 + 4) = o1;
        }
    }
}

// ---------------- aggregation: OUT[v] = sum_e coef*H[src] + dinv_v^2*H[v] + b --
// one wave per node; lane handles 2 channels (float2)
__global__ __launch_bounds__(256) void k_agg(const float* __restrict__ H,
                                             const int* __restrict__ rowptr,
                                             const int* __restrict__ csr,
                                             const float* __restrict__ dinv,
                                             const float* __restrict__ bias,
                                             float* __restrict__ OUT) {
    int wave = threadIdx.x >> 6;
    int lane = threadIdx.x & 63;
    int v = blockIdx.x * 4 + wave;
    if (v >= N_NODES) return;
    int c = lane * 2;
    float dv = dinv[v];
    float2 h = *(const float2*)(H + (long)v * 128 + c);
    float cs = dv * dv;
    float ax = h.x * cs, ay = h.y * cs;
    int e0 = rowptr[v], e1 = rowptr[v + 1];
    for (int e = e0; e < e1; ++e) {
        int s = csr[e];
        float coef = dinv[s] * dv;
        float2 hs = *(const float2*)(H + (long)s * 128 + c);
        ax += coef * hs.x;
        ay += coef * hs.y;
    }
    float2 bb = *(const float2*)(bias + c);
    ax += bb.x;
    ay += bb.y;
    float2 o = make_float2(ax, ay);
    *(float2*)(OUT + (long)v * 128 + c) = o;
}

// ---------------- BN stats: per-channel sum & sumsq ----------------
__global__ __launch_bounds__(256) void k_bnstats(const float* __restrict__ X,
                                                 float* __restrict__ st) {
    int ch = threadIdx.x & 127;
    int half = threadIdx.x >> 7;
    float s = 0.f, q = 0.f;
    for (int v = blockIdx.x * 2 + half; v < N_NODES; v += gridDim.x * 2) {
        float x = X[(long)v * 128 + ch];
        s += x;
        q += x * x;
    }
    __shared__ float sh[256];
    sh[threadIdx.x] = s;
    __syncthreads();
    if (half == 0) s += sh[threadIdx.x + 128];
    __syncthreads();
    sh[threadIdx.x] = q;
    __syncthreads();
    if (half == 0) {
        q += sh[threadIdx.x + 128];
        atomicAdd(&st[ch], s);
        atomicAdd(&st[128 + ch], q);
    }
}

// ---------------- BN finalize: scale/shift ----------------
__global__ void k_bnfin(const float* __restrict__ st, const float* __restrict__ g,
                        const float* __restrict__ be, float* __restrict__ coef) {
    int ch = threadIdx.x;  // 128 threads
    float inv_n = 1.0f / (float)N_NODES;
    float mean = st[ch] * inv_n;
    float var = st[128 + ch] * inv_n - mean * mean;
    float sc = g[ch] * rsqrtf(var + BN_EPS);
    coef[ch] = sc;
    coef[128 + ch] = be[ch] - mean * sc;
}

// ---------------- BN apply + ReLU (in place) ----------------
__global__ __launch_bounds__(256) void k_bnrelu(float* __restrict__ X,
                                                const float* __restrict__ coef) {
    const int total = N_NODES * 32;  // float4 count
    int stride = gridDim.x * 256;
    for (int i = blockIdx.x * 256 + threadIdx.x; i < total; i += stride) {
        float4 x = ((float4*)X)[i];
        int c0 = (i & 31) << 2;
        x.x = fmaxf(x.x * coef[c0] + coef[128 + c0], 0.f);
        x.y = fmaxf(x.y * coef[c0 + 1] + coef[128 + c0 + 1], 0.f);
        x.z = fmaxf(x.z * coef[c0 + 2] + coef[128 + c0 + 2], 0.f);
        x.w = fmaxf(x.w * coef[c0 + 3] + coef[128 + c0 + 3], 0.f);
        ((float4*)X)[i] = x;
    }
}

// ---------------- pooling: per-graph sum + counts (batch is sorted) -------
__global__ __launch_bounds__(256) void k_pool(const float* __restrict__ X,
                                              const int* __restrict__ batch,
                                              float* __restrict__ pool,
                                              float* __restrict__ cnt) {
    int ch = threadIdx.x & 127;
    int half = threadIdx.x >> 7;
    int start = blockIdx.x * 128 + half * 64;
    int end = min(start + 64, N_NODES);
    float acc = 0.f, cacc = 0.f;
    int cur = -1;
    for (int v = start; v < end; ++v) {
        int g = batch[v];
        if (g != cur) {
            if (cur >= 0) {
                atomicAdd(&pool[cur * 128 + ch], acc);
                if (ch == 0) atomicAdd(&cnt[cur], cacc);
            }
            cur = g;
            acc = 0.f;
            cacc = 0.f;
        }
        acc += X[(long)v * 128 + ch];
        cacc += 1.f;
    }
    if (cur >= 0) {
        atomicAdd(&pool[cur * 128 + ch], acc);
        if (ch == 0) atomicAdd(&cnt[cur], cacc);
    }
}

// ---------------- final MLP: [mean,sum] -> 128 relu -> 10 ----------------
__global__ __launch_bounds__(128) void k_mlp(const float* __restrict__ pool,
                                             const float* __restrict__ cnt,
                                             const float* __restrict__ w1,
                                             const float* __restrict__ b1,
                                             const float* __restrict__ w2,
                                             const float* __restrict__ b2,
                                             float* __restrict__ out) {
    __shared__ float h[256];
    __shared__ float h1[128];
    int g = blockIdx.x, t = threadIdx.x;
    float s = pool[g * 128 + t];
    float c = cnt[g];
    h[t] = s / fmaxf(c, 1.0f);  // mean
    h[128 + t] = s;             // sum
    __syncthreads();
    float acc = b1[t];
#pragma unroll 4
    for (int i = 0; i < 256; ++i) acc += h[i] * w1[i * 128 + t];
    h1[t] = fmaxf(acc, 0.f);
    __syncthreads();
    if (t < OUT_CH) {
        float o = b2[t];
#pragma unroll 4
        for (int j = 0; j < 128; ++j) o += h1[j] * w2[j * OUT_CH + t];
        out[g * OUT_CH + t] = o;
    }
}

extern "C" void kernel_launch(void* const* d_in, const int* in_sizes, int n_in,
                              void* d_out, int out_size, void* d_ws, size_t ws_size,
                              hipStream_t stream) {
    const float* x = (const float*)d_in[0];
    const int* ei = (const int*)d_in[1];
    const int* batch = (const int*)d_in[2];
    const float* W[3] = {(const float*)d_in[3], (const float*)d_in[7], (const float*)d_in[11]};
    const float* b[3] = {(const float*)d_in[4], (const float*)d_in[8], (const float*)d_in[12]};
    const float* gm[3] = {(const float*)d_in[5], (const float*)d_in[9], (const float*)d_in[13]};
    const float* be[3] = {(const float*)d_in[6], (const float*)d_in[10], (const float*)d_in[14]};
    const float* w1 = (const float*)d_in[15];
    const float* b1 = (const float*)d_in[16];
    const float* w2 = (const float*)d_in[17];
    const float* b2 = (const float*)d_in[18];
    float* out = (float*)d_out;

    float* ws = (float*)d_ws;
    float* H = ws + OFF_H;
    float* AGG = ws + OFF_AGG;
    int* deg = (int*)(ws + OFF_DEG);
    int* rowptr = (int*)(ws + OFF_ROWPTR);
    int* cursor = (int*)(ws + OFF_CURSOR);
    int* csr = (int*)(ws + OFF_CSR);
    float* dinv = ws + OFF_DINV;
    float* bnst = ws + OFF_BNST;
    float* bncoef = ws + OFF_BNCOEF;
    float* pool = ws + OFF_POOL;
    float* cnt = ws + OFF_CNT;
    int* bsum = (int*)(ws + OFF_BSUM);

    const int nb_scan = (N_NODES + 255) / 256;  // 196

    hipLaunchKernelGGL(k_init, dim3(nb_scan), dim3(256), 0, stream, deg, bnst, pool, cnt);
    hipLaunchKernelGGL(k_deg, dim3((N_EDGES + 255) / 256), dim3(256), 0, stream, ei, deg);
    hipLaunchKernelGGL(k_s1, dim3(nb_scan), dim3(256), 0, stream, deg, bsum);
    hipLaunchKernelGGL(k_s2, dim3(1), dim3(256), 0, stream, bsum, nb_scan);
    hipLaunchKernelGGL(k_s3, dim3(nb_scan), dim3(256), 0, stream, deg, bsum, rowptr, cursor);
    hipLaunchKernelGGL(k_scatter, dim3((N_EDGES + 255) / 256), dim3(256), 0, stream, ei, cursor, csr);
    hipLaunchKernelGGL(k_dinv, dim3(nb_scan), dim3(256), 0, stream, deg, dinv);

    const int gemm_blocks = (N_NODES + 63) / 64;
    const float* cur_x = x;
    for (int layer = 0; layer < 3; ++layer) {
        hipLaunchKernelGGL(k_gemm, dim3(gemm_blocks), dim3(256), 0, stream,
                           cur_x, W[layer], H, N_NODES);
        hipLaunchKernelGGL(k_agg, dim3((N_NODES + 3) / 4), dim3(256), 0, stream,
                           H, rowptr, csr, dinv, b[layer], AGG);
        hipLaunchKernelGGL(k_bnstats, dim3(512), dim3(256), 0, stream,
                           AGG, bnst + 256 * layer);
        hipLaunchKernelGGL(k_bnfin, dim3(1), dim3(128), 0, stream,
                           bnst + 256 * layer, gm[layer], be[layer], bncoef);
        hipLaunchKernelGGL(k_bnrelu, dim3(2048), dim3(256), 0, stream, AGG, bncoef);
        cur_x = AGG;
    }

    hipLaunchKernelGGL(k_pool, dim3((N_NODES + 127) / 128), dim3(256), 0, stream,
                       AGG, batch, pool, cnt);
    hipLaunchKernelGGL(k_mlp, dim3(N_GRAPHS), dim3(128), 0, stream,
                       pool, cnt, w1, b1, w2, b2, out);
}

// Round 3
// 661.511 us; speedup vs baseline: 1.0843x; 1.0843x over previous
//
#include <hip/hip_runtime.h>

#define N_NODES 50000
#define N_EDGES 800000
#define N_GRAPHS 256
#define HID 128
#define OUT_CH 10
#define BN_EPS 1e-5f

// ---------------- workspace layout (4-byte element offsets) ----------------
#define OFF_H       0            // bf16 H: 50000*128 ushort = 3,200,000 f32 slots
#define OFF_AGG     6400000      // 6,400,000 f32
#define OFF_DEG     12800000     // 50,000 i32
#define OFF_ROWPTR  12850000     // 50,001 i32
#define OFF_CURSOR  12900004     // 50,000 i32
#define OFF_CSR     12950004     // 800,000 i32
#define OFF_DINV    13750004     // 50,000 f32
#define OFF_BNST    13800004     // 3*256 f32 (sum[128], sumsq[128] per layer)
#define OFF_BNCOEF  13800772     // 256 f32 (scale[128], shift[128])
#define OFF_POOL    13801028     // 256*128 f32
#define OFF_CNT     13833796     // 256 f32
#define OFF_BSUM    13834052     // 256 i32

__device__ __forceinline__ ushort f2bf(float f) {
    union { float f; unsigned u; } v; v.f = f;
    unsigned r = v.u + 0x7FFFu + ((v.u >> 16) & 1u);   // RNE
    return (ushort)(r >> 16);
}
__device__ __forceinline__ float bf2f(unsigned u16) {
    return __uint_as_float(u16 << 16);
}

// ---------------- init: zero the accumulated regions ----------------
__global__ void k_init(int* deg, float* bnst, float* pool, float* cnt) {
    int i = blockIdx.x * 256 + threadIdx.x;
    if (i < N_NODES) deg[i] = 0;
    if (i < 768) bnst[i] = 0.f;
    if (i < N_GRAPHS * HID) pool[i] = 0.f;
    if (i < N_GRAPHS) cnt[i] = 0.f;
}

// ---------------- degree count (by dst) ----------------
__global__ void k_deg(const int* __restrict__ ei, int* __restrict__ deg) {
    int i = blockIdx.x * 256 + threadIdx.x;
    if (i < N_EDGES) atomicAdd(&deg[ei[N_EDGES + i]], 1);
}

// ---------------- 3-kernel exclusive scan over deg[50000] ----------------
__global__ void k_s1(const int* __restrict__ deg, int* __restrict__ bsum) {
    __shared__ int sh[256];
    int i = blockIdx.x * 256 + threadIdx.x;
    sh[threadIdx.x] = (i < N_NODES) ? deg[i] : 0;
    __syncthreads();
    for (int o = 128; o > 0; o >>= 1) {
        if (threadIdx.x < o) sh[threadIdx.x] += sh[threadIdx.x + o];
        __syncthreads();
    }
    if (threadIdx.x == 0) bsum[blockIdx.x] = sh[0];
}

__global__ void k_s2(int* __restrict__ bsum, int nb) {
    __shared__ int sh[256];
    int t = threadIdx.x;
    int v = (t < nb) ? bsum[t] : 0;
    sh[t] = v;
    __syncthreads();
    for (int o = 1; o < 256; o <<= 1) {
        int x = (t >= o) ? sh[t - o] : 0;
        __syncthreads();
        sh[t] += x;
        __syncthreads();
    }
    if (t < nb) bsum[t] = sh[t] - v;  // exclusive
}

// s3 also emits dinv = rsqrt(deg+1)
__global__ void k_s3(const int* __restrict__ deg, const int* __restrict__ bsum,
                     int* __restrict__ rowptr, int* __restrict__ cursor,
                     float* __restrict__ dinv) {
    __shared__ int sh[256];
    int t = threadIdx.x;
    int i = blockIdx.x * 256 + t;
    int v = (i < N_NODES) ? deg[i] : 0;
    sh[t] = v;
    __syncthreads();
    for (int o = 1; o < 256; o <<= 1) {
        int x = (t >= o) ? sh[t - o] : 0;
        __syncthreads();
        sh[t] += x;
        __syncthreads();
    }
    int ex = bsum[blockIdx.x] + sh[t] - v;
    if (i < N_NODES) {
        rowptr[i] = ex;
        cursor[i] = ex;
        dinv[i] = rsqrtf((float)(v + 1));
        if (i == N_NODES - 1) rowptr[N_NODES] = ex + v;
    }
}

// ---------------- scatter edges into CSR (by dst) ----------------
__global__ void k_scatter(const int* __restrict__ ei, int* __restrict__ cursor,
                          int* __restrict__ csr) {
    int i = blockIdx.x * 256 + threadIdx.x;
    if (i < N_EDGES) {
        int s = ei[i];
        int d = ei[N_EDGES + i];
        int pos = atomicAdd(&cursor[d], 1);
        csr[pos] = s;
    }
}

// ---------------- GEMM: Hb[n,128](bf16) = f(X)[n,128] @ W[128,128] ---------
// BN=1: f(x) = relu(x*sc[c] + sh[c]) applied while staging X (c = K-index).
// block 256 thr; tile 64 rows x 128 cols; K chunks of 32 staged in LDS;
// per-thread micro-tile 4 rows (stride 16) x 8 cols.
template <int BN>
__global__ __launch_bounds__(256) void k_gemm(const float* __restrict__ X,
                                              const float* __restrict__ W,
                                              ushort* __restrict__ Hb,
                                              const float* __restrict__ coef,
                                              int nrows) {
    __shared__ float Xs[64][36];    // +4 pad
    __shared__ float Ws[32][128];
    int t = threadIdx.x;
    int tx = t & 15;   // col group: cols tx*8 .. +8
    int ty = t >> 4;   // row group: rows ty + {0,16,32,48}
    int row0 = blockIdx.x * 64;

    float acc[4][8];
#pragma unroll
    for (int i = 0; i < 4; i++)
#pragma unroll
        for (int j = 0; j < 8; j++) acc[i][j] = 0.f;

    for (int k0 = 0; k0 < 128; k0 += 32) {
        // stage X tile: 64x32 = 512 float4; 2 per thread
#pragma unroll
        for (int p = 0; p < 2; p++) {
            int l = t + 256 * p;
            int r = l >> 3, ko = (l & 7) << 2;
            int gr = row0 + r;
            float4 v = make_float4(0.f, 0.f, 0.f, 0.f);
            if (gr < nrows) {
                v = *(const float4*)(X + (long)gr * 128 + k0 + ko);
                if (BN) {
                    float4 sc = *(const float4*)(coef + k0 + ko);
                    float4 sh = *(const float4*)(coef + 128 + k0 + ko);
                    v.x = fmaxf(v.x * sc.x + sh.x, 0.f);
                    v.y = fmaxf(v.y * sc.y + sh.y, 0.f);
                    v.z = fmaxf(v.z * sc.z + sh.z, 0.f);
                    v.w = fmaxf(v.w * sc.w + sh.w, 0.f);
                }
            }
            *(float4*)(&Xs[r][ko]) = v;
        }
        // stage W chunk: 32x128 = 1024 float4; 4 per thread
#pragma unroll
        for (int p = 0; p < 4; p++) {
            int l = t + 256 * p;
            int kk = l >> 5, off = (l & 31) << 2;
            *(float4*)(&Ws[kk][off]) = *(const float4*)(W + (long)(k0 + kk) * 128 + off);
        }
        __syncthreads();
#pragma unroll
        for (int k = 0; k < 32; k++) {
            float a[4];
            a[0] = Xs[ty][k];
            a[1] = Xs[ty + 16][k];
            a[2] = Xs[ty + 32][k];
            a[3] = Xs[ty + 48][k];
            float4 b0 = *(float4*)(&Ws[k][tx * 8]);
            float4 b1 = *(float4*)(&Ws[k][tx * 8 + 4]);
            float b[8] = {b0.x, b0.y, b0.z, b0.w, b1.x, b1.y, b1.z, b1.w};
#pragma unroll
            for (int i = 0; i < 4; i++)
#pragma unroll
                for (int j = 0; j < 8; j++) acc[i][j] += a[i] * b[j];
        }
        __syncthreads();
    }
#pragma unroll
    for (int i = 0; i < 4; i++) {
        int gr = row0 + ty + 16 * i;
        if (gr < nrows) {
            ushort o[8];
#pragma unroll
            for (int j = 0; j < 8; j++) o[j] = f2bf(acc[i][j]);
            *(uint4*)(Hb + (long)gr * 128 + tx * 8) = *(uint4*)o;
        }
    }
}

// ---------------- aggregation: OUT[v] = sum_e coef*Hb[src] + dinv_v^2*Hb[v] + b
// one wave per node; lane handles 2 channels (one 4B ushort2 load per row)
__global__ __launch_bounds__(256) void k_agg(const ushort* __restrict__ Hb,
                                             const int* __restrict__ rowptr,
                                             const int* __restrict__ csr,
                                             const float* __restrict__ dinv,
                                             const float* __restrict__ bias,
                                             float* __restrict__ OUT) {
    int wave = threadIdx.x >> 6;
    int lane = threadIdx.x & 63;
    int v = blockIdx.x * 4 + wave;
    if (v >= N_NODES) return;
    int c = lane * 2;
    float dv = dinv[v];
    unsigned p = *(const unsigned*)(Hb + (long)v * 128 + c);
    float cs = dv * dv;
    float ax = bf2f(p & 0xFFFFu) * cs, ay = bf2f(p >> 16) * cs;
    int e0 = rowptr[v], e1 = rowptr[v + 1];
    for (int e = e0; e < e1; ++e) {
        int s = csr[e];
        float coef = dinv[s] * dv;
        unsigned q = *(const unsigned*)(Hb + (long)s * 128 + c);
        ax += coef * bf2f(q & 0xFFFFu);
        ay += coef * bf2f(q >> 16);
    }
    float2 bb = *(const float2*)(bias + c);
    ax += bb.x;
    ay += bb.y;
    float2 o = make_float2(ax, ay);
    *(float2*)(OUT + (long)v * 128 + c) = o;
}

// ---------------- BN stats: per-channel sum & sumsq (on raw AGG) ----------
__global__ __launch_bounds__(256) void k_bnstats(const float* __restrict__ X,
                                                 float* __restrict__ st) {
    int ch = threadIdx.x & 127;
    int half = threadIdx.x >> 7;
    float s = 0.f, q = 0.f;
    for (int v = blockIdx.x * 2 + half; v < N_NODES; v += gridDim.x * 2) {
        float x = X[(long)v * 128 + ch];
        s += x;
        q += x * x;
    }
    __shared__ float sh[256];
    sh[threadIdx.x] = s;
    __syncthreads();
    if (half == 0) s += sh[threadIdx.x + 128];
    __syncthreads();
    sh[threadIdx.x] = q;
    __syncthreads();
    if (half == 0) {
        q += sh[threadIdx.x + 128];
        atomicAdd(&st[ch], s);
        atomicAdd(&st[128 + ch], q);
    }
}

// ---------------- BN finalize: scale/shift ----------------
__global__ void k_bnfin(const float* __restrict__ st, const float* __restrict__ g,
                        const float* __restrict__ be, float* __restrict__ coef) {
    int ch = threadIdx.x;  // 128 threads
    float inv_n = 1.0f / (float)N_NODES;
    float mean = st[ch] * inv_n;
    float var = st[128 + ch] * inv_n - mean * mean;
    float sc = g[ch] * rsqrtf(var + BN_EPS);
    coef[ch] = sc;
    coef[128 + ch] = be[ch] - mean * sc;
}

// ---------------- pooling with fused BN+ReLU (batch is sorted) -------------
__global__ __launch_bounds__(256) void k_pool(const float* __restrict__ X,
                                              const int* __restrict__ batch,
                                              const float* __restrict__ coef,
                                              float* __restrict__ pool,
                                              float* __restrict__ cnt) {
    int ch = threadIdx.x & 127;
    int half = threadIdx.x >> 7;
    int start = blockIdx.x * 128 + half * 64;
    int end = min(start + 64, N_NODES);
    float sc = coef[ch], sh = coef[128 + ch];
    float acc = 0.f, cacc = 0.f;
    int cur = -1;
    for (int v = start; v < end; ++v) {
        int g = batch[v];
        if (g != cur) {
            if (cur >= 0) {
                atomicAdd(&pool[cur * 128 + ch], acc);
                if (ch == 0) atomicAdd(&cnt[cur], cacc);
            }
            cur = g;
            acc = 0.f;
            cacc = 0.f;
        }
        acc += fmaxf(X[(long)v * 128 + ch] * sc + sh, 0.f);
        cacc += 1.f;
    }
    if (cur >= 0) {
        atomicAdd(&pool[cur * 128 + ch], acc);
        if (ch == 0) atomicAdd(&cnt[cur], cacc);
    }
}

// ---------------- final MLP: [mean,sum] -> 128 relu -> 10 ----------------
__global__ __launch_bounds__(128) void k_mlp(const float* __restrict__ pool,
                                             const float* __restrict__ cnt,
                                             const float* __restrict__ w1,
                                             const float* __restrict__ b1,
                                             const float* __restrict__ w2,
                                             const float* __restrict__ b2,
                                             float* __restrict__ out) {
    __shared__ float h[256];
    __shared__ float h1[128];
    int g = blockIdx.x, t = threadIdx.x;
    float s = pool[g * 128 + t];
    float c = cnt[g];
    h[t] = s / fmaxf(c, 1.0f);  // mean
    h[128 + t] = s;             // sum
    __syncthreads();
    float acc = b1[t];
#pragma unroll 4
    for (int i = 0; i < 256; ++i) acc += h[i] * w1[i * 128 + t];
    h1[t] = fmaxf(acc, 0.f);
    __syncthreads();
    if (t < OUT_CH) {
        float o = b2[t];
#pragma unroll 4
        for (int j = 0; j < 128; ++j) o += h1[j] * w2[j * OUT_CH + t];
        out[g * OUT_CH + t] = o;
    }
}

extern "C" void kernel_launch(void* const* d_in, const int* in_sizes, int n_in,
                              void* d_out, int out_size, void* d_ws, size_t ws_size,
                              hipStream_t stream) {
    const float* x = (const float*)d_in[0];
    const int* ei = (const int*)d_in[1];
    const int* batch = (const int*)d_in[2];
    const float* W[3] = {(const float*)d_in[3], (const float*)d_in[7], (const float*)d_in[11]};
    const float* b[3] = {(const float*)d_in[4], (const float*)d_in[8], (const float*)d_in[12]};
    const float* gm[3] = {(const float*)d_in[5], (const float*)d_in[9], (const float*)d_in[13]};
    const float* be[3] = {(const float*)d_in[6], (const float*)d_in[10], (const float*)d_in[14]};
    const float* w1 = (const float*)d_in[15];
    const float* b1 = (const float*)d_in[16];
    const float* w2 = (const float*)d_in[17];
    const float* b2 = (const float*)d_in[18];
    float* out = (float*)d_out;

    float* ws = (float*)d_ws;
    ushort* Hb = (ushort*)(ws + OFF_H);
    float* AGG = ws + OFF_AGG;
    int* deg = (int*)(ws + OFF_DEG);
    int* rowptr = (int*)(ws + OFF_ROWPTR);
    int* cursor = (int*)(ws + OFF_CURSOR);
    int* csr = (int*)(ws + OFF_CSR);
    float* dinv = ws + OFF_DINV;
    float* bnst = ws + OFF_BNST;
    float* bncoef = ws + OFF_BNCOEF;
    float* pool = ws + OFF_POOL;
    float* cnt = ws + OFF_CNT;
    int* bsum = (int*)(ws + OFF_BSUM);

    const int nb_scan = (N_NODES + 255) / 256;  // 196

    hipLaunchKernelGGL(k_init, dim3(nb_scan), dim3(256), 0, stream, deg, bnst, pool, cnt);
    hipLaunchKernelGGL(k_deg, dim3((N_EDGES + 255) / 256), dim3(256), 0, stream, ei, deg);
    hipLaunchKernelGGL(k_s1, dim3(nb_scan), dim3(256), 0, stream, deg, bsum);
    hipLaunchKernelGGL(k_s2, dim3(1), dim3(256), 0, stream, bsum, nb_scan);
    hipLaunchKernelGGL(k_s3, dim3(nb_scan), dim3(256), 0, stream, deg, bsum, rowptr, cursor, dinv);
    hipLaunchKernelGGL(k_scatter, dim3((N_EDGES + 255) / 256), dim3(256), 0, stream, ei, cursor, csr);

    const int gemm_blocks = (N_NODES + 63) / 64;
    for (int layer = 0; layer < 3; ++layer) {
        const float* cur_x = (layer == 0) ? x : AGG;
        if (layer == 0) {
            hipLaunchKernelGGL(k_gemm<0>, dim3(gemm_blocks), dim3(256), 0, stream,
                               cur_x, W[layer], Hb, (const float*)nullptr, N_NODES);
        } else {
            hipLaunchKernelGGL(k_gemm<1>, dim3(gemm_blocks), dim3(256), 0, stream,
                               cur_x, W[layer], Hb, bncoef, N_NODES);
        }
        hipLaunchKernelGGL(k_agg, dim3((N_NODES + 3) / 4), dim3(256), 0, stream,
                           Hb, rowptr, csr, dinv, b[layer], AGG);
        hipLaunchKernelGGL(k_bnstats, dim3(512), dim3(256), 0, stream,
                           AGG, bnst + 256 * layer);
        hipLaunchKernelGGL(k_bnfin, dim3(1), dim3(128), 0, stream,
                           bnst + 256 * layer, gm[layer], be[layer], bncoef);
    }

    hipLaunchKernelGGL(k_pool, dim3((N_NODES + 127) / 128), dim3(256), 0, stream,
                       AGG, batch, bncoef, pool, cnt);
    hipLaunchKernelGGL(k_mlp, dim3(N_GRAPHS), dim3(128), 0, stream,
                       pool, cnt, w1, b1, w2, b2, out);
}

// Round 6
// 505.570 us; speedup vs baseline: 1.4188x; 1.3084x over previous
//
#include <hip/hip_runtime.h>

#define N_NODES 50000
#define N_EDGES 800000
#define N_GRAPHS 256
#define HID 128
#define OUT_CH 10
#define BN_EPS 1e-5f

// ---------------- workspace layout (4-byte element offsets) ----------------
#define OFF_H       0            // bf16 H: 50000*128 ushort -> 3.2M f32 slots
#define OFF_BNPART  3134464      // 256*256 f32 partials (overlaps dead Hb tail; see note)
#define OFF_CSRD    3200000      // 800,000 f32 (dinv[src] per CSR slot)
#define OFF_WBT     4000000      // 3 * 128*136 ushort = 26,112 f32 slots
#define OFF_AGG     6400000      // 6,400,000 f32
#define OFF_DEG     12800000     // 50,000 i32
#define OFF_ROWPTR  12850000     // 50,001 i32
#define OFF_CURSOR  12900004     // 50,000 i32
#define OFF_CSR     12950004     // 800,000 i32
#define OFF_DINV    13750004     // 50,000 f32
#define OFF_BNCOEF  13800004     // 256 f32 (scale[128], shift[128])
#define OFF_POOL    13800260     // 256*128 f32
#define OFF_CNT     13833028     // 256 f32
#define OFF_BSUM    13833284     // 256 i32
// BNPART note: lives in Hb rows 48976..50000. Per-layer order is
// gemm(writes Hb) -> agg(reads Hb) -> bnstats(writes BNPART; Hb dead) ->
// bnred(reads BNPART) -> next gemm(rewrites Hb). No overlap hazard.

#define WBT_PITCH 136            // ushorts per row (128 + 8 pad)

typedef __attribute__((ext_vector_type(8))) short bf16x8;
typedef __attribute__((ext_vector_type(4))) float f32x4;

__device__ __forceinline__ ushort f2bf(float f) {
    union { float f; unsigned u; } v; v.f = f;
    unsigned r = v.u + 0x7FFFu + ((v.u >> 16) & 1u);   // RNE
    return (ushort)(r >> 16);
}
__device__ __forceinline__ float bf2f(unsigned u16) {
    return __uint_as_float(u16 << 16);
}

// ---------------- init: zero deg ----------------
__global__ void k_init(int* deg) {
    int i = blockIdx.x * 256 + threadIdx.x;
    if (i < N_NODES) deg[i] = 0;
}

// ---------------- degree count (by dst) ----------------
__global__ void k_deg(const int* __restrict__ ei, int* __restrict__ deg) {
    int i = blockIdx.x * 256 + threadIdx.x;
    if (i < N_EDGES) atomicAdd(&deg[ei[N_EDGES + i]], 1);
}

// ---------------- 3-kernel exclusive scan over deg[50000] ----------------
__global__ void k_s1(const int* __restrict__ deg, int* __restrict__ bsum) {
    __shared__ int sh[256];
    int i = blockIdx.x * 256 + threadIdx.x;
    sh[threadIdx.x] = (i < N_NODES) ? deg[i] : 0;
    __syncthreads();
    for (int o = 128; o > 0; o >>= 1) {
        if (threadIdx.x < o) sh[threadIdx.x] += sh[threadIdx.x + o];
        __syncthreads();
    }
    if (threadIdx.x == 0) bsum[blockIdx.x] = sh[0];
}

__global__ void k_s2(int* __restrict__ bsum, int nb) {
    __shared__ int sh[256];
    int t = threadIdx.x;
    int v = (t < nb) ? bsum[t] : 0;
    sh[t] = v;
    __syncthreads();
    for (int o = 1; o < 256; o <<= 1) {
        int x = (t >= o) ? sh[t - o] : 0;
        __syncthreads();
        sh[t] += x;
        __syncthreads();
    }
    if (t < nb) bsum[t] = sh[t] - v;  // exclusive
}

// s3 also emits dinv = rsqrt(deg+1)
__global__ void k_s3(const int* __restrict__ deg, const int* __restrict__ bsum,
                     int* __restrict__ rowptr, int* __restrict__ cursor,
                     float* __restrict__ dinv) {
    __shared__ int sh[256];
    int t = threadIdx.x;
    int i = blockIdx.x * 256 + t;
    int v = (i < N_NODES) ? deg[i] : 0;
    sh[t] = v;
    __syncthreads();
    for (int o = 1; o < 256; o <<= 1) {
        int x = (t >= o) ? sh[t - o] : 0;
        __syncthreads();
        sh[t] += x;
        __syncthreads();
    }
    int ex = bsum[blockIdx.x] + sh[t] - v;
    if (i < N_NODES) {
        rowptr[i] = ex;
        cursor[i] = ex;
        dinv[i] = rsqrtf((float)(v + 1));
        if (i == N_NODES - 1) rowptr[N_NODES] = ex + v;
    }
}

// ---------------- scatter edges into CSR (by dst); order canonicalized later
__global__ void k_scatter(const int* __restrict__ ei, int* __restrict__ cursor,
                          int* __restrict__ csr) {
    int i = blockIdx.x * 256 + threadIdx.x;
    if (i < N_EDGES) {
        int s = ei[i];
        int d = ei[N_EDGES + i];
        int pos = atomicAdd(&cursor[d], 1);
        csr[pos] = s;
    }
}

// ---------------- canonicalize: sort each segment ascending, fill csrd -----
// one wave per node; 64-lane bitonic sort via shfl_xor (deg<=64 always here).
__global__ __launch_bounds__(256) void k_sortseg(const int* __restrict__ rowptr,
                                                 int* __restrict__ csr,
                                                 const float* __restrict__ dinv,
                                                 float* __restrict__ csrd) {
    int wave = threadIdx.x >> 6, lane = threadIdx.x & 63;
    int v = blockIdx.x * 4 + wave;
    if (v >= N_NODES) return;
    int e0 = rowptr[v], deg = rowptr[v + 1] - e0;
    if (deg <= 64) {
        int val = (lane < deg) ? csr[e0 + lane] : 0x7FFFFFFF;
#pragma unroll
        for (int k = 2; k <= 64; k <<= 1)
#pragma unroll
            for (int j = k >> 1; j > 0; j >>= 1) {
                int other = __shfl_xor(val, j);
                bool up = ((lane & k) == 0);
                bool lower = ((lane & j) == 0);
                int mn = min(val, other), mx = max(val, other);
                val = (up == lower) ? mn : mx;
            }
        if (lane < deg) {
            csr[e0 + lane] = val;
            csrd[e0 + lane] = dinv[val];
        }
    } else {
        if (lane == 0) {
            for (int i = e0 + 1; i < e0 + deg; ++i) {
                int key = csr[i];
                int j = i - 1;
                while (j >= e0 && csr[j] > key) { csr[j + 1] = csr[j]; --j; }
                csr[j + 1] = key;
            }
        }
        for (int e = e0 + lane; e < e0 + deg; e += 64) csrd[e] = dinv[csr[e]];
    }
}

// ---------------- W prep: Wbt[c][k] = bf16(W[k][c]), pitch 136 -------------
__global__ void k_wprep(const float* __restrict__ W, ushort* __restrict__ Wbt) {
    int i = blockIdx.x * 256 + threadIdx.x;
    if (i < 16384) {
        int k = i >> 7, c = i & 127;
        Wbt[c * WBT_PITCH + k] = f2bf(W[i]);
    }
}

// ---------------- MFMA GEMM: Hb[n,128](bf16) = f(X)[n,128] @ W -------------
// BN=1: f(x) = relu(x*sc[c] + sh[c]) while building A fragments.
template <int BN>
__global__ __launch_bounds__(256) void k_gemm(const float* __restrict__ X,
                                              const ushort* __restrict__ Wbt,
                                              ushort* __restrict__ Hb,
                                              const float* __restrict__ coef,
                                              int nrows) {
    __shared__ __align__(16) ushort Wt[128 * WBT_PITCH];
    int t = threadIdx.x;
    for (int i = t; i < 2176; i += 256)
        ((uint4*)Wt)[i] = ((const uint4*)Wbt)[i];
    __syncthreads();

    int wv = t >> 6, l = t & 63;
    int m = l & 15;
    int kg = l >> 4;
    int row = blockIdx.x * 64 + wv * 16 + m;
    bool valid = row < nrows;
    const float* xr = X + (long)row * 128;

    f32x4 acc[8];
#pragma unroll
    for (int n = 0; n < 8; ++n) acc[n] = (f32x4){0.f, 0.f, 0.f, 0.f};

#pragma unroll
    for (int t4 = 0; t4 < 4; ++t4) {
        int k0 = t4 * 32 + kg * 8;
        float xv[8];
        if (valid) {
            float4 u0 = *(const float4*)(xr + k0);
            float4 u1 = *(const float4*)(xr + k0 + 4);
            if (BN) {
                float4 s0 = *(const float4*)(coef + k0);
                float4 s1 = *(const float4*)(coef + k0 + 4);
                float4 h0 = *(const float4*)(coef + 128 + k0);
                float4 h1 = *(const float4*)(coef + 128 + k0 + 4);
                u0.x = fmaxf(u0.x * s0.x + h0.x, 0.f);
                u0.y = fmaxf(u0.y * s0.y + h0.y, 0.f);
                u0.z = fmaxf(u0.z * s0.z + h0.z, 0.f);
                u0.w = fmaxf(u0.w * s0.w + h0.w, 0.f);
                u1.x = fmaxf(u1.x * s1.x + h1.x, 0.f);
                u1.y = fmaxf(u1.y * s1.y + h1.y, 0.f);
                u1.z = fmaxf(u1.z * s1.z + h1.z, 0.f);
                u1.w = fmaxf(u1.w * s1.w + h1.w, 0.f);
            }
            xv[0] = u0.x; xv[1] = u0.y; xv[2] = u0.z; xv[3] = u0.w;
            xv[4] = u1.x; xv[5] = u1.y; xv[6] = u1.z; xv[7] = u1.w;
        } else {
#pragma unroll
            for (int j = 0; j < 8; ++j) xv[j] = 0.f;
        }
        union { ushort u[8]; bf16x8 v; } A;
#pragma unroll
        for (int j = 0; j < 8; ++j) A.u[j] = f2bf(xv[j]);

#pragma unroll
        for (int n = 0; n < 8; ++n) {
            bf16x8 b = *(const bf16x8*)(&Wt[(n * 16 + m) * WBT_PITCH + k0]);
            acc[n] = __builtin_amdgcn_mfma_f32_16x16x32_bf16(A.v, b, acc[n], 0, 0, 0);
        }
    }

    int srow0 = blockIdx.x * 64 + wv * 16 + kg * 4;
#pragma unroll
    for (int n = 0; n < 8; ++n)
#pragma unroll
        for (int r = 0; r < 4; ++r) {
            int rr = srow0 + r;
            if (rr < nrows) Hb[(long)rr * 128 + n * 16 + m] = f2bf(acc[n][r]);
        }
}

// ---------------- aggregation (MLP version, deterministic CSR order) -------
__global__ __launch_bounds__(256) void k_agg(const ushort* __restrict__ Hb,
                                             const int* __restrict__ rowptr,
                                             const int* __restrict__ csr,
                                             const float* __restrict__ csrd,
                                             const float* __restrict__ dinv,
                                             const float* __restrict__ bias,
                                             float* __restrict__ OUT) {
    int wave = threadIdx.x >> 6, lane = threadIdx.x & 63;
    int v = blockIdx.x * 4 + wave;
    if (v >= N_NODES) return;
    int half = lane >> 5, qd = lane & 31;
    int c = qd * 4;
    float dv = dinv[v];
    int e0 = rowptr[v];
    int deg = rowptr[v + 1] - e0;
    float a0 = 0.f, a1 = 0.f, a2 = 0.f, a3 = 0.f;

    for (int base = 0; base < deg; base += 64) {
        int mye = base + lane;
        int idx = 0; float dvi = 0.f;
        if (mye < deg) { idx = csr[e0 + mye]; dvi = csrd[e0 + mye]; }
        int n = min(64, deg - base);
        int P = (n + 1) >> 1;
        int p = 0;
#define EDGE(pp) { \
        int sl = 2 * (pp) + half; \
        int s = __shfl(idx, sl); \
        float cf = __shfl(dvi, sl) * dv; \
        uint2 qv = *(const uint2*)(Hb + (long)s * 128 + c); \
        a0 += cf * bf2f(qv.x & 0xFFFFu); \
        a1 += cf * bf2f(qv.x >> 16); \
        a2 += cf * bf2f(qv.y & 0xFFFFu); \
        a3 += cf * bf2f(qv.y >> 16); }
        for (; p + 4 <= P; p += 4) { EDGE(p) EDGE(p + 1) EDGE(p + 2) EDGE(p + 3) }
        for (; p < P; ++p) { EDGE(p) }
#undef EDGE
    }
    a0 += __shfl_xor(a0, 32);
    a1 += __shfl_xor(a1, 32);
    a2 += __shfl_xor(a2, 32);
    a3 += __shfl_xor(a3, 32);
    if (half == 0) {
        uint2 qv = *(const uint2*)(Hb + (long)v * 128 + c);
        float cs = dv * dv;
        float4 bb = *(const float4*)(bias + c);
        float4 o;
        o.x = a0 + cs * bf2f(qv.x & 0xFFFFu) + bb.x;
        o.y = a1 + cs * bf2f(qv.x >> 16) + bb.y;
        o.z = a2 + cs * bf2f(qv.y & 0xFFFFu) + bb.z;
        o.w = a3 + cs * bf2f(qv.y >> 16) + bb.w;
        *(float4*)(OUT + (long)v * 128 + c) = o;
    }
}

// ---------------- BN stats phase 1: per-block partials (no atomics) --------
__global__ __launch_bounds__(256) void k_bnstats(const float* __restrict__ X,
                                                 float* __restrict__ part) {
    int ch = threadIdx.x & 127;
    int half = threadIdx.x >> 7;
    float s = 0.f, q = 0.f;
    for (int v = blockIdx.x * 2 + half; v < N_NODES; v += 512) {
        float x = X[(long)v * 128 + ch];
        s += x;
        q += x * x;
    }
    __shared__ float sh[256];
    sh[threadIdx.x] = s;
    __syncthreads();
    float s2 = (half == 0) ? s + sh[threadIdx.x + 128] : 0.f;
    __syncthreads();
    sh[threadIdx.x] = q;
    __syncthreads();
    if (half == 0) {
        float q2 = q + sh[threadIdx.x + 128];
        part[blockIdx.x * 256 + ch] = s2;
        part[blockIdx.x * 256 + 128 + ch] = q2;
    }
}

// ---------------- BN stats phase 2: fixed-order reduce + coef --------------
__global__ void k_bnred(const float* __restrict__ part, const float* __restrict__ g,
                        const float* __restrict__ be, float* __restrict__ coef) {
    int t = threadIdx.x;        // 256: stat = t>>7, ch = t&127
    int ch = t & 127, stat = t >> 7;
    float acc = 0.f;
    for (int b = 0; b < 256; ++b) acc += part[b * 256 + stat * 128 + ch];
    __shared__ float sh[256];
    sh[t] = acc;
    __syncthreads();
    if (stat == 0) {
        float inv_n = 1.0f / (float)N_NODES;
        float mean = acc * inv_n;
        float var = sh[128 + ch] * inv_n - mean * mean;
        float sc = g[ch] * rsqrtf(var + BN_EPS);
        coef[ch] = sc;
        coef[128 + ch] = be[ch] - mean * sc;
    }
}

// ---------------- pooling: one block per graph, deterministic --------------
__global__ __launch_bounds__(256) void k_pool(const float* __restrict__ X,
                                              const int* __restrict__ batch,
                                              const float* __restrict__ coef,
                                              float* __restrict__ pool,
                                              float* __restrict__ cnt) {
    __shared__ int bounds[2];
    int g = blockIdx.x, t = threadIdx.x;
    if (t < 2) {
        int target = g + t;
        int lo = 0, hi = N_NODES;
        while (lo < hi) {
            int mid = (lo + hi) >> 1;
            if (batch[mid] < target) lo = mid + 1; else hi = mid;
        }
        bounds[t] = lo;
    }
    __syncthreads();
    int start = bounds[0], end = bounds[1];
    int ch = t & 127, half = t >> 7;
    float sc = coef[ch], sh = coef[128 + ch];
    float acc = 0.f;
    for (int v = start + half; v < end; v += 2)
        acc += fmaxf(X[(long)v * 128 + ch] * sc + sh, 0.f);
    __shared__ float red[256];
    red[t] = acc;
    __syncthreads();
    if (half == 0) {
        pool[g * 128 + ch] = red[ch] + red[128 + ch];
        if (ch == 0) cnt[g] = (float)(end - start);
    }
}

// ---------------- final MLP: [mean,sum] -> 128 relu -> 10 ----------------
__global__ __launch_bounds__(128) void k_mlp(const float* __restrict__ pool,
                                             const float* __restrict__ cnt,
                                             const float* __restrict__ w1,
                                             const float* __restrict__ b1,
                                             const float* __restrict__ w2,
                                             const float* __restrict__ b2,
                                             float* __restrict__ out) {
    __shared__ float h[256];
    __shared__ float h1[128];
    int g = blockIdx.x, t = threadIdx.x;
    float s = pool[g * 128 + t];
    float c = cnt[g];
    h[t] = s / fmaxf(c, 1.0f);  // mean
    h[128 + t] = s;             // sum
    __syncthreads();
    float acc = b1[t];
#pragma unroll 4
    for (int i = 0; i < 256; ++i) acc += h[i] * w1[i * 128 + t];
    h1[t] = fmaxf(acc, 0.f);
    __syncthreads();
    if (t < OUT_CH) {
        float o = b2[t];
#pragma unroll 4
        for (int j = 0; j < 128; ++j) o += h1[j] * w2[j * OUT_CH + t];
        out[g * OUT_CH + t] = o;
    }
}

extern "C" void kernel_launch(void* const* d_in, const int* in_sizes, int n_in,
                              void* d_out, int out_size, void* d_ws, size_t ws_size,
                              hipStream_t stream) {
    const float* x = (const float*)d_in[0];
    const int* ei = (const int*)d_in[1];
    const int* batch = (const int*)d_in[2];
    const float* W[3] = {(const float*)d_in[3], (const float*)d_in[7], (const float*)d_in[11]};
    const float* b[3] = {(const float*)d_in[4], (const float*)d_in[8], (const float*)d_in[12]};
    const float* gm[3] = {(const float*)d_in[5], (const float*)d_in[9], (const float*)d_in[13]};
    const float* be[3] = {(const float*)d_in[6], (const float*)d_in[10], (const float*)d_in[14]};
    const float* w1 = (const float*)d_in[15];
    const float* b1 = (const float*)d_in[16];
    const float* w2 = (const float*)d_in[17];
    const float* b2 = (const float*)d_in[18];
    float* out = (float*)d_out;

    float* ws = (float*)d_ws;
    ushort* Hb = (ushort*)(ws + OFF_H);
    float* bnpart = ws + OFF_BNPART;
    float* csrd = ws + OFF_CSRD;
    ushort* Wbt = (ushort*)(ws + OFF_WBT);
    float* AGG = ws + OFF_AGG;
    int* deg = (int*)(ws + OFF_DEG);
    int* rowptr = (int*)(ws + OFF_ROWPTR);
    int* cursor = (int*)(ws + OFF_CURSOR);
    int* csr = (int*)(ws + OFF_CSR);
    float* dinv = ws + OFF_DINV;
    float* bncoef = ws + OFF_BNCOEF;
    float* pool = ws + OFF_POOL;
    float* cnt = ws + OFF_CNT;
    int* bsum = (int*)(ws + OFF_BSUM);

    const int nb_scan = (N_NODES + 255) / 256;  // 196
    const int nb_node4 = (N_NODES + 3) / 4;     // 12500

    hipLaunchKernelGGL(k_init, dim3(nb_scan), dim3(256), 0, stream, deg);
    hipLaunchKernelGGL(k_deg, dim3((N_EDGES + 255) / 256), dim3(256), 0, stream, ei, deg);
    hipLaunchKernelGGL(k_s1, dim3(nb_scan), dim3(256), 0, stream, deg, bsum);
    hipLaunchKernelGGL(k_s2, dim3(1), dim3(256), 0, stream, bsum, nb_scan);
    hipLaunchKernelGGL(k_s3, dim3(nb_scan), dim3(256), 0, stream, deg, bsum, rowptr, cursor, dinv);
    hipLaunchKernelGGL(k_scatter, dim3((N_EDGES + 255) / 256), dim3(256), 0, stream,
                       ei, cursor, csr);
    hipLaunchKernelGGL(k_sortseg, dim3(nb_node4), dim3(256), 0, stream,
                       rowptr, csr, dinv, csrd);
    for (int layer = 0; layer < 3; ++layer)
        hipLaunchKernelGGL(k_wprep, dim3(64), dim3(256), 0, stream,
                           W[layer], Wbt + layer * 128 * WBT_PITCH);

    const int gemm_blocks = (N_NODES + 63) / 64;  // 782
    for (int layer = 0; layer < 3; ++layer) {
        const float* cur_x = (layer == 0) ? x : AGG;
        const ushort* wbt_l = Wbt + layer * 128 * WBT_PITCH;
        if (layer == 0) {
            hipLaunchKernelGGL(k_gemm<0>, dim3(gemm_blocks), dim3(256), 0, stream,
                               cur_x, wbt_l, Hb, (const float*)nullptr, N_NODES);
        } else {
            hipLaunchKernelGGL(k_gemm<1>, dim3(gemm_blocks), dim3(256), 0, stream,
                               cur_x, wbt_l, Hb, bncoef, N_NODES);
        }
        hipLaunchKernelGGL(k_agg, dim3(nb_node4), dim3(256), 0, stream,
                           Hb, rowptr, csr, csrd, dinv, b[layer], AGG);
        hipLaunchKernelGGL(k_bnstats, dim3(256), dim3(256), 0, stream, AGG, bnpart);
        hipLaunchKernelGGL(k_bnred, dim3(1), dim3(256), 0, stream,
                           bnpart, gm[layer], be[layer], bncoef);
    }

    hipLaunchKernelGGL(k_pool, dim3(N_GRAPHS), dim3(256), 0, stream,
                       AGG, batch, bncoef, pool, cnt);
    hipLaunchKernelGGL(k_mlp, dim3(N_GRAPHS), dim3(128), 0, stream,
                       pool, cnt, w1, b1, w2, b2, out);
}

// Round 7
// 480.005 us; speedup vs baseline: 1.4944x; 1.0533x over previous
//
#include <hip/hip_runtime.h>

#define N_NODES 50000
#define N_EDGES 800000
#define N_GRAPHS 256
#define HID 128
#define OUT_CH 10
#define BN_EPS 1e-5f

#define NBUCKET 98               // ceil(50000/512) buckets of 512 nodes
#define BCAP 10240               // per-bucket pair capacity (mean 8192, sd ~90)

// ---------------- workspace layout (4-byte element offsets) ----------------
#define OFF_H       0            // bf16 H: 50000*128 ushort -> 3.2M f32 slots
#define OFF_BNPART  3134464      // 256*256 f32 partials (overlaps dead Hb tail)
#define OFF_CSRD    3200000      // 800,000 f32 (dinv[src] per CSR slot)
#define OFF_WBT     4000000      // 3 * 128*136 ushort = 26,112 f32 slots
#define OFF_AGG     6400000      // 6,400,000 f32; bucketBuf overlaps (build only)
#define OFF_ROWPTR  12850000     // 50,001 i32
#define OFF_CSR     12950004     // 800,000 i32
#define OFF_DINV    13750004     // 50,000 f32
#define OFF_BNCOEF  13800004     // 256 f32 (scale[128], shift[128])
#define OFF_POOL    13800260     // 256*128 f32
#define OFF_CNT     13833028     // 256 f32
#define OFF_BCNT    13833284     // NBUCKET i32
#define OFF_BSTART  13833444     // NBUCKET+1 i32
// bucketBuf: int2[NBUCKET*BCAP] at OFF_AGG (8 MB). Used only before the first
// k_agg writes AGG — gemm0/agg0 run after csrbuild completes. No hazard.
// BNPART: Hb rows 48976..50000; per-layer order gemm(Hb)->agg(reads Hb)->
// bnstats(writes BNPART)->bnred->next gemm. No hazard.

#define WBT_PITCH 136            // ushorts per row (128 + 8 pad)

typedef __attribute__((ext_vector_type(8))) short bf16x8;
typedef __attribute__((ext_vector_type(4))) float f32x4;

__device__ __forceinline__ ushort f2bf(float f) {
    union { float f; unsigned u; } v; v.f = f;
    unsigned r = v.u + 0x7FFFu + ((v.u >> 16) & 1u);   // RNE
    return (ushort)(r >> 16);
}
__device__ __forceinline__ float bf2f(unsigned u16) {
    return __uint_as_float(u16 << 16);
}

// ---------------- zero bucket counters ----------------
__global__ void k_zero(int* bcnt) {
    int i = threadIdx.x;
    if (i < NBUCKET) bcnt[i] = 0;
}

// ---------------- bucket edges by dst>>9 (block-reserved append) ----------
__global__ __launch_bounds__(256) void k_bucket(const int* __restrict__ ei,
                                                int* __restrict__ bcnt,
                                                int2* __restrict__ buf) {
    __shared__ int histL[NBUCKET], baseL[NBUCKET], curL[NBUCKET];
    int t = threadIdx.x;
    if (t < NBUCKET) histL[t] = 0;
    __syncthreads();
    const int stride = gridDim.x * 256;
    for (int i = blockIdx.x * 256 + t; i < N_EDGES; i += stride)
        atomicAdd(&histL[ei[N_EDGES + i] >> 9], 1);
    __syncthreads();
    if (t < NBUCKET) {
        baseL[t] = atomicAdd(&bcnt[t], histL[t]);
        curL[t] = 0;
    }
    __syncthreads();
    for (int i = blockIdx.x * 256 + t; i < N_EDGES; i += stride) {
        int s = ei[i];
        int d = ei[N_EDGES + i];
        int b = d >> 9;
        int p = baseL[b] + atomicAdd(&curL[b], 1);
        if (p < BCAP) buf[b * BCAP + p] = make_int2(s, d);
    }
}

// ---------------- tiny scan over bucket counts ----------------
__global__ void k_bscan(const int* __restrict__ bcnt, int* __restrict__ bstart,
                        int* __restrict__ rowptr) {
    if (threadIdx.x == 0) {
        int acc = 0;
        for (int b = 0; b < NBUCKET; ++b) { bstart[b] = acc; acc += bcnt[b]; }
        bstart[NBUCKET] = acc;
        rowptr[N_NODES] = acc;
    }
}

// ---------------- per-bucket CSR build: hist, scan, place, sort, write -----
// one block (512 thr) per bucket; deterministic via ascending-src sort.
__global__ __launch_bounds__(512) void k_csrbuild(const int2* __restrict__ buf,
                                                  const int* __restrict__ bcnt,
                                                  const int* __restrict__ bstart,
                                                  int* __restrict__ rowptr,
                                                  int* __restrict__ csr,
                                                  float* __restrict__ dinv) {
    __shared__ int off[512];
    __shared__ int cur[512];
    __shared__ int img[BCAP];
    int b = blockIdx.x, t = threadIdx.x;
    int node0 = b << 9;
    int cnt = bcnt[b];
    int ebase = bstart[b];
    const int2* mybuf = buf + b * BCAP;

    off[t] = 0;
    __syncthreads();
    for (int e = t; e < cnt; e += 512)
        atomicAdd(&off[mybuf[e].y - node0], 1);
    __syncthreads();
    int mydeg = off[t];
    // inclusive block scan (Hillis-Steele)
    for (int o = 1; o < 512; o <<= 1) {
        int x = (t >= o) ? off[t - o] : 0;
        __syncthreads();
        off[t] += x;
        __syncthreads();
    }
    int inc = off[t];
    cur[t] = inc - mydeg;
    int node = node0 + t;
    if (node < N_NODES) {
        rowptr[node] = ebase + inc - mydeg;
        dinv[node] = rsqrtf((float)(mydeg + 1));
    }
    __syncthreads();
    for (int e = t; e < cnt; e += 512) {
        int2 pr = mybuf[e];
        int p = atomicAdd(&cur[pr.y - node0], 1);
        img[p] = pr.x;
    }
    __syncthreads();
    // insertion-sort each node's segment ascending (canonical order)
    int lo = inc - mydeg;
    for (int i = lo + 1; i < inc; ++i) {
        int key = img[i];
        int j = i - 1;
        while (j >= lo && img[j] > key) { img[j + 1] = img[j]; --j; }
        img[j + 1] = key;
    }
    __syncthreads();
    for (int e = t; e < cnt; e += 512)
        csr[ebase + e] = img[e];
}

// ---------------- csrd[e] = dinv[csr[e]] ----------------
__global__ void k_fill(const int* __restrict__ csr, const float* __restrict__ dinv,
                       float* __restrict__ csrd) {
    int i = blockIdx.x * 1024 + threadIdx.x;
    if (i < N_EDGES) csrd[i] = dinv[csr[i]];
}

// ---------------- W prep: Wbt[c][k] = bf16(W[k][c]), pitch 136 -------------
__global__ void k_wprep(const float* __restrict__ W, ushort* __restrict__ Wbt) {
    int i = blockIdx.x * 256 + threadIdx.x;
    if (i < 16384) {
        int k = i >> 7, c = i & 127;
        Wbt[c * WBT_PITCH + k] = f2bf(W[i]);
    }
}

// ---------------- MFMA GEMM: Hb[n,128](bf16) = f(X)[n,128] @ W -------------
template <int BN>
__global__ __launch_bounds__(256) void k_gemm(const float* __restrict__ X,
                                              const ushort* __restrict__ Wbt,
                                              ushort* __restrict__ Hb,
                                              const float* __restrict__ coef,
                                              int nrows) {
    __shared__ __align__(16) ushort Wt[128 * WBT_PITCH];
    int t = threadIdx.x;
    for (int i = t; i < 2176; i += 256)
        ((uint4*)Wt)[i] = ((const uint4*)Wbt)[i];
    __syncthreads();

    int wv = t >> 6, l = t & 63;
    int m = l & 15;
    int kg = l >> 4;
    int row = blockIdx.x * 64 + wv * 16 + m;
    bool valid = row < nrows;
    const float* xr = X + (long)row * 128;

    f32x4 acc[8];
#pragma unroll
    for (int n = 0; n < 8; ++n) acc[n] = (f32x4){0.f, 0.f, 0.f, 0.f};

#pragma unroll
    for (int t4 = 0; t4 < 4; ++t4) {
        int k0 = t4 * 32 + kg * 8;
        float xv[8];
        if (valid) {
            float4 u0 = *(const float4*)(xr + k0);
            float4 u1 = *(const float4*)(xr + k0 + 4);
            if (BN) {
                float4 s0 = *(const float4*)(coef + k0);
                float4 s1 = *(const float4*)(coef + k0 + 4);
                float4 h0 = *(const float4*)(coef + 128 + k0);
                float4 h1 = *(const float4*)(coef + 128 + k0 + 4);
                u0.x = fmaxf(u0.x * s0.x + h0.x, 0.f);
                u0.y = fmaxf(u0.y * s0.y + h0.y, 0.f);
                u0.z = fmaxf(u0.z * s0.z + h0.z, 0.f);
                u0.w = fmaxf(u0.w * s0.w + h0.w, 0.f);
                u1.x = fmaxf(u1.x * s1.x + h1.x, 0.f);
                u1.y = fmaxf(u1.y * s1.y + h1.y, 0.f);
                u1.z = fmaxf(u1.z * s1.z + h1.z, 0.f);
                u1.w = fmaxf(u1.w * s1.w + h1.w, 0.f);
            }
            xv[0] = u0.x; xv[1] = u0.y; xv[2] = u0.z; xv[3] = u0.w;
            xv[4] = u1.x; xv[5] = u1.y; xv[6] = u1.z; xv[7] = u1.w;
        } else {
#pragma unroll
            for (int j = 0; j < 8; ++j) xv[j] = 0.f;
        }
        union { ushort u[8]; bf16x8 v; } A;
#pragma unroll
        for (int j = 0; j < 8; ++j) A.u[j] = f2bf(xv[j]);

#pragma unroll
        for (int n = 0; n < 8; ++n) {
            bf16x8 b = *(const bf16x8*)(&Wt[(n * 16 + m) * WBT_PITCH + k0]);
            acc[n] = __builtin_amdgcn_mfma_f32_16x16x32_bf16(A.v, b, acc[n], 0, 0, 0);
        }
    }

    int srow0 = blockIdx.x * 64 + wv * 16 + kg * 4;
#pragma unroll
    for (int n = 0; n < 8; ++n)
#pragma unroll
        for (int r = 0; r < 4; ++r) {
            int rr = srow0 + r;
            if (rr < nrows) Hb[(long)rr * 128 + n * 16 + m] = f2bf(acc[n][r]);
        }
}

// ---------------- aggregation (deterministic CSR order) --------------------
__global__ __launch_bounds__(256) void k_agg(const ushort* __restrict__ Hb,
                                             const int* __restrict__ rowptr,
                                             const int* __restrict__ csr,
                                             const float* __restrict__ csrd,
                                             const float* __restrict__ dinv,
                                             const float* __restrict__ bias,
                                             float* __restrict__ OUT) {
    int wave = threadIdx.x >> 6, lane = threadIdx.x & 63;
    int v = blockIdx.x * 4 + wave;
    if (v >= N_NODES) return;
    int half = lane >> 5, qd = lane & 31;
    int c = qd * 4;
    float dv = dinv[v];
    int e0 = rowptr[v];
    int deg = rowptr[v + 1] - e0;
    float a0 = 0.f, a1 = 0.f, a2 = 0.f, a3 = 0.f;

    for (int base = 0; base < deg; base += 64) {
        int mye = base + lane;
        int idx = 0; float dvi = 0.f;
        if (mye < deg) { idx = csr[e0 + mye]; dvi = csrd[e0 + mye]; }
        int n = min(64, deg - base);
        int P = (n + 1) >> 1;
        int p = 0;
#define EDGE(pp) { \
        int sl = 2 * (pp) + half; \
        int s = __shfl(idx, sl); \
        float cf = __shfl(dvi, sl) * dv; \
        uint2 qv = *(const uint2*)(Hb + (long)s * 128 + c); \
        a0 += cf * bf2f(qv.x & 0xFFFFu); \
        a1 += cf * bf2f(qv.x >> 16); \
        a2 += cf * bf2f(qv.y & 0xFFFFu); \
        a3 += cf * bf2f(qv.y >> 16); }
        for (; p + 4 <= P; p += 4) { EDGE(p) EDGE(p + 1) EDGE(p + 2) EDGE(p + 3) }
        for (; p < P; ++p) { EDGE(p) }
#undef EDGE
    }
    a0 += __shfl_xor(a0, 32);
    a1 += __shfl_xor(a1, 32);
    a2 += __shfl_xor(a2, 32);
    a3 += __shfl_xor(a3, 32);
    if (half == 0) {
        uint2 qv = *(const uint2*)(Hb + (long)v * 128 + c);
        float cs = dv * dv;
        float4 bb = *(const float4*)(bias + c);
        float4 o;
        o.x = a0 + cs * bf2f(qv.x & 0xFFFFu) + bb.x;
        o.y = a1 + cs * bf2f(qv.x >> 16) + bb.y;
        o.z = a2 + cs * bf2f(qv.y & 0xFFFFu) + bb.z;
        o.w = a3 + cs * bf2f(qv.y >> 16) + bb.w;
        *(float4*)(OUT + (long)v * 128 + c) = o;
    }
}

// ---------------- BN stats phase 1: per-block partials (no atomics) --------
__global__ __launch_bounds__(256) void k_bnstats(const float* __restrict__ X,
                                                 float* __restrict__ part) {
    int ch = threadIdx.x & 127;
    int half = threadIdx.x >> 7;
    float s = 0.f, q = 0.f;
    for (int v = blockIdx.x * 2 + half; v < N_NODES; v += 512) {
        float x = X[(long)v * 128 + ch];
        s += x;
        q += x * x;
    }
    __shared__ float sh[256];
    sh[threadIdx.x] = s;
    __syncthreads();
    float s2 = (half == 0) ? s + sh[threadIdx.x + 128] : 0.f;
    __syncthreads();
    sh[threadIdx.x] = q;
    __syncthreads();
    if (half == 0) {
        float q2 = q + sh[threadIdx.x + 128];
        part[blockIdx.x * 256 + ch] = s2;
        part[blockIdx.x * 256 + 128 + ch] = q2;
    }
}

// ---------------- BN stats phase 2: fixed-order reduce + coef --------------
__global__ void k_bnred(const float* __restrict__ part, const float* __restrict__ g,
                        const float* __restrict__ be, float* __restrict__ coef) {
    int t = threadIdx.x;
    int ch = t & 127, stat = t >> 7;
    float acc = 0.f;
    for (int b = 0; b < 256; ++b) acc += part[b * 256 + stat * 128 + ch];
    __shared__ float sh[256];
    sh[t] = acc;
    __syncthreads();
    if (stat == 0) {
        float inv_n = 1.0f / (float)N_NODES;
        float mean = acc * inv_n;
        float var = sh[128 + ch] * inv_n - mean * mean;
        float sc = g[ch] * rsqrtf(var + BN_EPS);
        coef[ch] = sc;
        coef[128 + ch] = be[ch] - mean * sc;
    }
}

// ---------------- pooling: one block per graph, deterministic --------------
__global__ __launch_bounds__(256) void k_pool(const float* __restrict__ X,
                                              const int* __restrict__ batch,
                                              const float* __restrict__ coef,
                                              float* __restrict__ pool,
                                              float* __restrict__ cnt) {
    __shared__ int bounds[2];
    int g = blockIdx.x, t = threadIdx.x;
    if (t < 2) {
        int target = g + t;
        int lo = 0, hi = N_NODES;
        while (lo < hi) {
            int mid = (lo + hi) >> 1;
            if (batch[mid] < target) lo = mid + 1; else hi = mid;
        }
        bounds[t] = lo;
    }
    __syncthreads();
    int start = bounds[0], end = bounds[1];
    int ch = t & 127, half = t >> 7;
    float sc = coef[ch], sh = coef[128 + ch];
    float acc = 0.f;
    for (int v = start + half; v < end; v += 2)
        acc += fmaxf(X[(long)v * 128 + ch] * sc + sh, 0.f);
    __shared__ float red[256];
    red[t] = acc;
    __syncthreads();
    if (half == 0) {
        pool[g * 128 + ch] = red[ch] + red[128 + ch];
        if (ch == 0) cnt[g] = (float)(end - start);
    }
}

// ---------------- final MLP: [mean,sum] -> 128 relu -> 10 ----------------
__global__ __launch_bounds__(128) void k_mlp(const float* __restrict__ pool,
                                             const float* __restrict__ cnt,
                                             const float* __restrict__ w1,
                                             const float* __restrict__ b1,
                                             const float* __restrict__ w2,
                                             const float* __restrict__ b2,
                                             float* __restrict__ out) {
    __shared__ float h[256];
    __shared__ float h1[128];
    int g = blockIdx.x, t = threadIdx.x;
    float s = pool[g * 128 + t];
    float c = cnt[g];
    h[t] = s / fmaxf(c, 1.0f);  // mean
    h[128 + t] = s;             // sum
    __syncthreads();
    float acc = b1[t];
#pragma unroll 4
    for (int i = 0; i < 256; ++i) acc += h[i] * w1[i * 128 + t];
    h1[t] = fmaxf(acc, 0.f);
    __syncthreads();
    if (t < OUT_CH) {
        float o = b2[t];
#pragma unroll 4
        for (int j = 0; j < 128; ++j) o += h1[j] * w2[j * OUT_CH + t];
        out[g * OUT_CH + t] = o;
    }
}

extern "C" void kernel_launch(void* const* d_in, const int* in_sizes, int n_in,
                              void* d_out, int out_size, void* d_ws, size_t ws_size,
                              hipStream_t stream) {
    const float* x = (const float*)d_in[0];
    const int* ei = (const int*)d_in[1];
    const int* batch = (const int*)d_in[2];
    const float* W[3] = {(const float*)d_in[3], (const float*)d_in[7], (const float*)d_in[11]};
    const float* b[3] = {(const float*)d_in[4], (const float*)d_in[8], (const float*)d_in[12]};
    const float* gm[3] = {(const float*)d_in[5], (const float*)d_in[9], (const float*)d_in[13]};
    const float* be[3] = {(const float*)d_in[6], (const float*)d_in[10], (const float*)d_in[14]};
    const float* w1 = (const float*)d_in[15];
    const float* b1 = (const float*)d_in[16];
    const float* w2 = (const float*)d_in[17];
    const float* b2 = (const float*)d_in[18];
    float* out = (float*)d_out;

    float* ws = (float*)d_ws;
    ushort* Hb = (ushort*)(ws + OFF_H);
    float* bnpart = ws + OFF_BNPART;
    float* csrd = ws + OFF_CSRD;
    ushort* Wbt = (ushort*)(ws + OFF_WBT);
    float* AGG = ws + OFF_AGG;
    int2* bucketBuf = (int2*)(ws + OFF_AGG);
    int* rowptr = (int*)(ws + OFF_ROWPTR);
    int* csr = (int*)(ws + OFF_CSR);
    float* dinv = ws + OFF_DINV;
    float* bncoef = ws + OFF_BNCOEF;
    float* pool = ws + OFF_POOL;
    float* cnt = ws + OFF_CNT;
    int* bcnt = (int*)(ws + OFF_BCNT);
    int* bstart = (int*)(ws + OFF_BSTART);

    const int nb_node4 = (N_NODES + 3) / 4;     // 12500

    hipLaunchKernelGGL(k_zero, dim3(1), dim3(128), 0, stream, bcnt);
    hipLaunchKernelGGL(k_bucket, dim3(392), dim3(256), 0, stream, ei, bcnt, bucketBuf);
    hipLaunchKernelGGL(k_bscan, dim3(1), dim3(64), 0, stream, bcnt, bstart, rowptr);
    hipLaunchKernelGGL(k_csrbuild, dim3(NBUCKET), dim3(512), 0, stream,
                       bucketBuf, bcnt, bstart, rowptr, csr, dinv);
    hipLaunchKernelGGL(k_fill, dim3((N_EDGES + 1023) / 1024), dim3(1024), 0, stream,
                       csr, dinv, csrd);
    for (int layer = 0; layer < 3; ++layer)
        hipLaunchKernelGGL(k_wprep, dim3(64), dim3(256), 0, stream,
                           W[layer], Wbt + layer * 128 * WBT_PITCH);

    const int gemm_blocks = (N_NODES + 63) / 64;  // 782
    for (int layer = 0; layer < 3; ++layer) {
        const float* cur_x = (layer == 0) ? x : AGG;
        const ushort* wbt_l = Wbt + layer * 128 * WBT_PITCH;
        if (layer == 0) {
            hipLaunchKernelGGL(k_gemm<0>, dim3(gemm_blocks), dim3(256), 0, stream,
                               cur_x, wbt_l, Hb, (const float*)nullptr, N_NODES);
        } else {
            hipLaunchKernelGGL(k_gemm<1>, dim3(gemm_blocks), dim3(256), 0, stream,
                               cur_x, wbt_l, Hb, bncoef, N_NODES);
        }
        hipLaunchKernelGGL(k_agg, dim3(nb_node4), dim3(256), 0, stream,
                           Hb, rowptr, csr, csrd, dinv, b[layer], AGG);
        hipLaunchKernelGGL(k_bnstats, dim3(256), dim3(256), 0, stream, AGG, bnpart);
        hipLaunchKernelGGL(k_bnred, dim3(1), dim3(256), 0, stream,
                           bnpart, gm[layer], be[layer], bncoef);
    }

    hipLaunchKernelGGL(k_pool, dim3(N_GRAPHS), dim3(256), 0, stream,
                       AGG, batch, bncoef, pool, cnt);
    hipLaunchKernelGGL(k_mlp, dim3(N_GRAPHS), dim3(128), 0, stream,
                       pool, cnt, w1, b1, w2, b2, out);
}

// Round 9
// 449.073 us; speedup vs baseline: 1.5973x; 1.0689x over previous
//
#include <hip/hip_runtime.h>

#define N_NODES 50000
#define N_EDGES 800000
#define N_GRAPHS 256
#define HID 128
#define OUT_CH 10
#define BN_EPS 1e-5f

#define NBUCKET 98               // ceil(50000/512) buckets of 512 nodes
#define BCAP 10240               // per-bucket pair capacity (mean 8192, sd ~90)

// ---------------- workspace layout (4-byte element offsets) ----------------
#define OFF_H       0            // bf16 H: 50000*128 ushort -> 3.2M f32 slots
#define OFF_BNPART  3134464      // 256*256 f32 partials (overlaps dead Hb tail)
#define OFF_CSRD    3200000      // 800,000 f32 (dinv[src] per CSR slot)
#define OFF_WBT     4000000      // 3 * 128*136 ushort = 26,112 f32 slots
#define OFF_AGG     6400000      // 6,400,000 f32; bucketBuf overlaps (build only)
#define OFF_ROWPTR  12850000     // 50,001 i32
#define OFF_CSR     12950004     // 800,000 i32
#define OFF_DINV    13750004     // 50,000 f32
#define OFF_BNCOEF  13800004     // 256 f32 (scale[128], shift[128])
#define OFF_POOL    13800260     // 256*128 f32
#define OFF_CNT     13833028     // 256 f32
#define OFF_BCNT    13833284     // NBUCKET i32
#define OFF_BSTART  13833444     // NBUCKET+1 i32
// bucketBuf: int2[NBUCKET*BCAP] at OFF_AGG (8 MB). Used only before the first
// k_agg writes AGG. BNPART: Hb rows 48976..50000, dead when bnstats runs.

#define WBT_PITCH 136            // ushorts per row (128 + 8 pad)

typedef __attribute__((ext_vector_type(8))) short bf16x8;
typedef __attribute__((ext_vector_type(4))) float f32x4;

__device__ __forceinline__ ushort f2bf(float f) {
    union { float f; unsigned u; } v; v.f = f;
    unsigned r = v.u + 0x7FFFu + ((v.u >> 16) & 1u);   // RNE
    return (ushort)(r >> 16);
}
__device__ __forceinline__ float bf2f(unsigned u16) {
    return __uint_as_float(u16 << 16);
}

// ---------------- zero bucket counters ----------------
__global__ void k_zero(int* bcnt) {
    int i = threadIdx.x;
    if (i < NBUCKET) bcnt[i] = 0;
}

// ---------------- bucket edges by dst>>9 (block-reserved append) ----------
__global__ __launch_bounds__(256) void k_bucket(const int* __restrict__ ei,
                                                int* __restrict__ bcnt,
                                                int2* __restrict__ buf) {
    __shared__ int histL[NBUCKET], baseL[NBUCKET], curL[NBUCKET];
    int t = threadIdx.x;
    if (t < NBUCKET) histL[t] = 0;
    __syncthreads();
    const int stride = gridDim.x * 256;
    for (int i = blockIdx.x * 256 + t; i < N_EDGES; i += stride)
        atomicAdd(&histL[ei[N_EDGES + i] >> 9], 1);
    __syncthreads();
    if (t < NBUCKET) {
        baseL[t] = atomicAdd(&bcnt[t], histL[t]);
        curL[t] = 0;
    }
    __syncthreads();
    for (int i = blockIdx.x * 256 + t; i < N_EDGES; i += stride) {
        int s = ei[i];
        int d = ei[N_EDGES + i];
        int b = d >> 9;
        int p = baseL[b] + atomicAdd(&curL[b], 1);
        if (p < BCAP) buf[b * BCAP + p] = make_int2(s, d);
    }
}

// ---------------- tiny scan over bucket counts ----------------
__global__ void k_bscan(const int* __restrict__ bcnt, int* __restrict__ bstart,
                        int* __restrict__ rowptr) {
    if (threadIdx.x == 0) {
        int acc = 0;
        for (int b = 0; b < NBUCKET; ++b) { bstart[b] = acc; acc += bcnt[b]; }
        bstart[NBUCKET] = acc;
        rowptr[N_NODES] = acc;
    }
}

// ---------------- per-bucket CSR build: hist, scan, direct scatter ---------
// order within a segment is arbitrary here; k_sortseg canonicalizes it.
__global__ __launch_bounds__(512) void k_csrbuild(const int2* __restrict__ buf,
                                                  const int* __restrict__ bcnt,
                                                  const int* __restrict__ bstart,
                                                  int* __restrict__ rowptr,
                                                  int* __restrict__ csr,
                                                  float* __restrict__ dinv) {
    __shared__ int off[512];
    __shared__ int cur[512];
    int b = blockIdx.x, t = threadIdx.x;
    int node0 = b << 9;
    int cnt = bcnt[b];
    int ebase = bstart[b];
    const int2* mybuf = buf + b * BCAP;

    off[t] = 0;
    __syncthreads();
    for (int e = t; e < cnt; e += 512)
        atomicAdd(&off[mybuf[e].y - node0], 1);
    __syncthreads();
    int mydeg = off[t];
    // inclusive block scan (Hillis-Steele)
    for (int o = 1; o < 512; o <<= 1) {
        int x = (t >= o) ? off[t - o] : 0;
        __syncthreads();
        off[t] += x;
        __syncthreads();
    }
    int inc = off[t];
    cur[t] = ebase + inc - mydeg;
    int node = node0 + t;
    if (node < N_NODES) {
        rowptr[node] = ebase + inc - mydeg;
        dinv[node] = rsqrtf((float)(mydeg + 1));
    }
    __syncthreads();
    for (int e = t; e < cnt; e += 512) {
        int2 pr = mybuf[e];
        int p = atomicAdd(&cur[pr.y - node0], 1);
        csr[p] = pr.x;
    }
}

// ---------------- canonicalize: sort each segment ascending, fill csrd -----
// one wave per node; 64-lane bitonic sort via shfl_xor (register-only).
__global__ __launch_bounds__(256) void k_sortseg(const int* __restrict__ rowptr,
                                                 int* __restrict__ csr,
                                                 const float* __restrict__ dinv,
                                                 float* __restrict__ csrd) {
    int wave = threadIdx.x >> 6, lane = threadIdx.x & 63;
    int v = blockIdx.x * 4 + wave;
    if (v >= N_NODES) return;
    int e0 = rowptr[v], deg = rowptr[v + 1] - e0;
    if (deg <= 64) {
        int val = (lane < deg) ? csr[e0 + lane] : 0x7FFFFFFF;
#pragma unroll
        for (int k = 2; k <= 64; k <<= 1)
#pragma unroll
            for (int j = k >> 1; j > 0; j >>= 1) {
                int other = __shfl_xor(val, j);
                bool up = ((lane & k) == 0);
                bool lower = ((lane & j) == 0);
                int mn = min(val, other), mx = max(val, other);
                val = (up == lower) ? mn : mx;
            }
        if (lane < deg) {
            csr[e0 + lane] = val;
            csrd[e0 + lane] = dinv[val];
        }
    } else {
        if (lane == 0) {
            for (int i = e0 + 1; i < e0 + deg; ++i) {
                int key = csr[i];
                int j = i - 1;
                while (j >= e0 && csr[j] > key) { csr[j + 1] = csr[j]; --j; }
                csr[j + 1] = key;
            }
        }
        for (int e = e0 + lane; e < e0 + deg; e += 64) csrd[e] = dinv[csr[e]];
    }
}

// ---------------- W prep: Wbt[c][k] = bf16(W[k][c]), pitch 136 -------------
__global__ void k_wprep(const float* __restrict__ W, ushort* __restrict__ Wbt) {
    int i = blockIdx.x * 256 + threadIdx.x;
    if (i < 16384) {
        int k = i >> 7, c = i & 127;
        Wbt[c * WBT_PITCH + k] = f2bf(W[i]);
    }
}

// ---------------- MFMA GEMM: Hb[n,128](bf16) = f(X)[n,128] @ W -------------
template <int BN>
__global__ __launch_bounds__(256) void k_gemm(const float* __restrict__ X,
                                              const ushort* __restrict__ Wbt,
                                              ushort* __restrict__ Hb,
                                              const float* __restrict__ coef,
                                              int nrows) {
    __shared__ __align__(16) ushort Wt[128 * WBT_PITCH];
    int t = threadIdx.x;
    for (int i = t; i < 2176; i += 256)
        ((uint4*)Wt)[i] = ((const uint4*)Wbt)[i];
    __syncthreads();

    int wv = t >> 6, l = t & 63;
    int m = l & 15;
    int kg = l >> 4;
    int row = blockIdx.x * 64 + wv * 16 + m;
    bool valid = row < nrows;
    const float* xr = X + (long)row * 128;

    f32x4 acc[8];
#pragma unroll
    for (int n = 0; n < 8; ++n) acc[n] = (f32x4){0.f, 0.f, 0.f, 0.f};

#pragma unroll
    for (int t4 = 0; t4 < 4; ++t4) {
        int k0 = t4 * 32 + kg * 8;
        float xv[8];
        if (valid) {
            float4 u0 = *(const float4*)(xr + k0);
            float4 u1 = *(const float4*)(xr + k0 + 4);
            if (BN) {
                float4 s0 = *(const float4*)(coef + k0);
                float4 s1 = *(const float4*)(coef + k0 + 4);
                float4 h0 = *(const float4*)(coef + 128 + k0);
                float4 h1 = *(const float4*)(coef + 128 + k0 + 4);
                u0.x = fmaxf(u0.x * s0.x + h0.x, 0.f);
                u0.y = fmaxf(u0.y * s0.y + h0.y, 0.f);
                u0.z = fmaxf(u0.z * s0.z + h0.z, 0.f);
                u0.w = fmaxf(u0.w * s0.w + h0.w, 0.f);
                u1.x = fmaxf(u1.x * s1.x + h1.x, 0.f);
                u1.y = fmaxf(u1.y * s1.y + h1.y, 0.f);
                u1.z = fmaxf(u1.z * s1.z + h1.z, 0.f);
                u1.w = fmaxf(u1.w * s1.w + h1.w, 0.f);
            }
            xv[0] = u0.x; xv[1] = u0.y; xv[2] = u0.z; xv[3] = u0.w;
            xv[4] = u1.x; xv[5] = u1.y; xv[6] = u1.z; xv[7] = u1.w;
        } else {
#pragma unroll
            for (int j = 0; j < 8; ++j) xv[j] = 0.f;
        }
        union { ushort u[8]; bf16x8 v; } A;
#pragma unroll
        for (int j = 0; j < 8; ++j) A.u[j] = f2bf(xv[j]);

#pragma unroll
        for (int n = 0; n < 8; ++n) {
            bf16x8 b = *(const bf16x8*)(&Wt[(n * 16 + m) * WBT_PITCH + k0]);
            acc[n] = __builtin_amdgcn_mfma_f32_16x16x32_bf16(A.v, b, acc[n], 0, 0, 0);
        }
    }

    int srow0 = blockIdx.x * 64 + wv * 16 + kg * 4;
#pragma unroll
    for (int n = 0; n < 8; ++n)
#pragma unroll
        for (int r = 0; r < 4; ++r) {
            int rr = srow0 + r;
            if (rr < nrows) Hb[(long)rr * 128 + n * 16 + m] = f2bf(acc[n][r]);
        }
}

// ---------------- aggregation (deterministic CSR order) --------------------
__global__ __launch_bounds__(256) void k_agg(const ushort* __restrict__ Hb,
                                             const int* __restrict__ rowptr,
                                             const int* __restrict__ csr,
                                             const float* __restrict__ csrd,
                                             const float* __restrict__ dinv,
                                             const float* __restrict__ bias,
                                             float* __restrict__ OUT) {
    int wave = threadIdx.x >> 6, lane = threadIdx.x & 63;
    int v = blockIdx.x * 4 + wave;
    if (v >= N_NODES) return;
    int half = lane >> 5, qd = lane & 31;
    int c = qd * 4;
    float dv = dinv[v];
    int e0 = rowptr[v];
    int deg = rowptr[v + 1] - e0;
    float a0 = 0.f, a1 = 0.f, a2 = 0.f, a3 = 0.f;

    for (int base = 0; base < deg; base += 64) {
        int mye = base + lane;
        int idx = 0; float dvi = 0.f;
        if (mye < deg) { idx = csr[e0 + mye]; dvi = csrd[e0 + mye]; }
        int n = min(64, deg - base);
        int P = (n + 1) >> 1;
        int p = 0;
#define EDGE(pp) { \
        int sl = 2 * (pp) + half; \
        int s = __shfl(idx, sl); \
        float cf = __shfl(dvi, sl) * dv; \
        uint2 qv = *(const uint2*)(Hb + (long)s * 128 + c); \
        a0 += cf * bf2f(qv.x & 0xFFFFu); \
        a1 += cf * bf2f(qv.x >> 16); \
        a2 += cf * bf2f(qv.y & 0xFFFFu); \
        a3 += cf * bf2f(qv.y >> 16); }
        for (; p + 4 <= P; p += 4) { EDGE(p) EDGE(p + 1) EDGE(p + 2) EDGE(p + 3) }
        for (; p < P; ++p) { EDGE(p) }
#undef EDGE
    }
    a0 += __shfl_xor(a0, 32);
    a1 += __shfl_xor(a1, 32);
    a2 += __shfl_xor(a2, 32);
    a3 += __shfl_xor(a3, 32);
    if (half == 0) {
        uint2 qv = *(const uint2*)(Hb + (long)v * 128 + c);
        float cs = dv * dv;
        float4 bb = *(const float4*)(bias + c);
        float4 o;
        o.x = a0 + cs * bf2f(qv.x & 0xFFFFu) + bb.x;
        o.y = a1 + cs * bf2f(qv.x >> 16) + bb.y;
        o.z = a2 + cs * bf2f(qv.y & 0xFFFFu) + bb.z;
        o.w = a3 + cs * bf2f(qv.y >> 16) + bb.w;
        *(float4*)(OUT + (long)v * 128 + c) = o;
    }
}

// ---------------- BN stats phase 1: per-block partials (no atomics) --------
__global__ __launch_bounds__(256) void k_bnstats(const float* __restrict__ X,
                                                 float* __restrict__ part) {
    int ch = threadIdx.x & 127;
    int half = threadIdx.x >> 7;
    float s = 0.f, q = 0.f;
    for (int v = blockIdx.x * 2 + half; v < N_NODES; v += 512) {
        float x = X[(long)v * 128 + ch];
        s += x;
        q += x * x;
    }
    __shared__ float sh[256];
    sh[threadIdx.x] = s;
    __syncthreads();
    float s2 = (half == 0) ? s + sh[threadIdx.x + 128] : 0.f;
    __syncthreads();
    sh[threadIdx.x] = q;
    __syncthreads();
    if (half == 0) {
        float q2 = q + sh[threadIdx.x + 128];
        part[blockIdx.x * 256 + ch] = s2;
        part[blockIdx.x * 256 + 128 + ch] = q2;
    }
}

// ---------------- BN stats phase 2: fixed-order reduce + coef --------------
__global__ void k_bnred(const float* __restrict__ part, const float* __restrict__ g,
                        const float* __restrict__ be, float* __restrict__ coef) {
    int t = threadIdx.x;
    int ch = t & 127, stat = t >> 7;
    float acc = 0.f;
    for (int b = 0; b < 256; ++b) acc += part[b * 256 + stat * 128 + ch];
    __shared__ float sh[256];
    sh[t] = acc;
    __syncthreads();
    if (stat == 0) {
        float inv_n = 1.0f / (float)N_NODES;
        float mean = acc * inv_n;
        float var = sh[128 + ch] * inv_n - mean * mean;
        float sc = g[ch] * rsqrtf(var + BN_EPS);
        coef[ch] = sc;
        coef[128 + ch] = be[ch] - mean * sc;
    }
}

// ---------------- pooling: one block per graph, deterministic --------------
__global__ __launch_bounds__(256) void k_pool(const float* __restrict__ X,
                                              const int* __restrict__ batch,
                                              const float* __restrict__ coef,
                                              float* __restrict__ pool,
                                              float* __restrict__ cnt) {
    __shared__ int bounds[2];
    int g = blockIdx.x, t = threadIdx.x;
    if (t < 2) {
        int target = g + t;
        int lo = 0, hi = N_NODES;
        while (lo < hi) {
            int mid = (lo + hi) >> 1;
            if (batch[mid] < target) lo = mid + 1; else hi = mid;
        }
        bounds[t] = lo;
    }
    __syncthreads();
    int start = bounds[0], end = bounds[1];
    int ch = t & 127, half = t >> 7;
    float sc = coef[ch], sh = coef[128 + ch];
    float acc = 0.f;
    for (int v = start + half; v < end; v += 2)
        acc += fmaxf(X[(long)v * 128 + ch] * sc + sh, 0.f);
    __shared__ float red[256];
    red[t] = acc;
    __syncthreads();
    if (half == 0) {
        pool[g * 128 + ch] = red[ch] + red[128 + ch];
        if (ch == 0) cnt[g] = (float)(end - start);
    }
}

// ---------------- final MLP: [mean,sum] -> 128 relu -> 10 ----------------
__global__ __launch_bounds__(128) void k_mlp(const float* __restrict__ pool,
                                             const float* __restrict__ cnt,
                                             const float* __restrict__ w1,
                                             const float* __restrict__ b1,
                                             const float* __restrict__ w2,
                                             const float* __restrict__ b2,
                                             float* __restrict__ out) {
    __shared__ float h[256];
    __shared__ float h1[128];
    int g = blockIdx.x, t = threadIdx.x;
    float s = pool[g * 128 + t];
    float c = cnt[g];
    h[t] = s / fmaxf(c, 1.0f);  // mean
    h[128 + t] = s;             // sum
    __syncthreads();
    float acc = b1[t];
#pragma unroll 4
    for (int i = 0; i < 256; ++i) acc += h[i] * w1[i * 128 + t];
    h1[t] = fmaxf(acc, 0.f);
    __syncthreads();
    if (t < OUT_CH) {
        float o = b2[t];
#pragma unroll 4
        for (int j = 0; j < 128; ++j) o += h1[j] * w2[j * OUT_CH + t];
        out[g * OUT_CH + t] = o;
    }
}

extern "C" void kernel_launch(void* const* d_in, const int* in_sizes, int n_in,
                              void* d_out, int out_size, void* d_ws, size_t ws_size,
                              hipStream_t stream) {
    const float* x = (const float*)d_in[0];
    const int* ei = (const int*)d_in[1];
    const int* batch = (const int*)d_in[2];
    const float* W[3] = {(const float*)d_in[3], (const float*)d_in[7], (const float*)d_in[11]};
    const float* b[3] = {(const float*)d_in[4], (const float*)d_in[8], (const float*)d_in[12]};
    const float* gm[3] = {(const float*)d_in[5], (const float*)d_in[9], (const float*)d_in[13]};
    const float* be[3] = {(const float*)d_in[6], (const float*)d_in[10], (const float*)d_in[14]};
    const float* w1 = (const float*)d_in[15];
    const float* b1 = (const float*)d_in[16];
    const float* w2 = (const float*)d_in[17];
    const float* b2 = (const float*)d_in[18];
    float* out = (float*)d_out;

    float* ws = (float*)d_ws;
    ushort* Hb = (ushort*)(ws + OFF_H);
    float* bnpart = ws + OFF_BNPART;
    float* csrd = ws + OFF_CSRD;
    ushort* Wbt = (ushort*)(ws + OFF_WBT);
    float* AGG = ws + OFF_AGG;
    int2* bucketBuf = (int2*)(ws + OFF_AGG);
    int* rowptr = (int*)(ws + OFF_ROWPTR);
    int* csr = (int*)(ws + OFF_CSR);
    float* dinv = ws + OFF_DINV;
    float* bncoef = ws + OFF_BNCOEF;
    float* pool = ws + OFF_POOL;
    float* cnt = ws + OFF_CNT;
    int* bcnt = (int*)(ws + OFF_BCNT);
    int* bstart = (int*)(ws + OFF_BSTART);

    const int nb_node4 = (N_NODES + 3) / 4;     // 12500

    hipLaunchKernelGGL(k_zero, dim3(1), dim3(128), 0, stream, bcnt);
    hipLaunchKernelGGL(k_bucket, dim3(392), dim3(256), 0, stream, ei, bcnt, bucketBuf);
    hipLaunchKernelGGL(k_bscan, dim3(1), dim3(64), 0, stream, bcnt, bstart, rowptr);
    hipLaunchKernelGGL(k_csrbuild, dim3(NBUCKET), dim3(512), 0, stream,
                       bucketBuf, bcnt, bstart, rowptr, csr, dinv);
    hipLaunchKernelGGL(k_sortseg, dim3(nb_node4), dim3(256), 0, stream,
                       rowptr, csr, dinv, csrd);
    for (int layer = 0; layer < 3; ++layer)
        hipLaunchKernelGGL(k_wprep, dim3(64), dim3(256), 0, stream,
                           W[layer], Wbt + layer * 128 * WBT_PITCH);

    const int gemm_blocks = (N_NODES + 63) / 64;  // 782
    for (int layer = 0; layer < 3; ++layer) {
        const float* cur_x = (layer == 0) ? x : AGG;
        const ushort* wbt_l = Wbt + layer * 128 * WBT_PITCH;
        if (layer == 0) {
            hipLaunchKernelGGL(k_gemm<0>, dim3(gemm_blocks), dim3(256), 0, stream,
                               cur_x, wbt_l, Hb, (const float*)nullptr, N_NODES);
        } else {
            hipLaunchKernelGGL(k_gemm<1>, dim3(gemm_blocks), dim3(256), 0, stream,
                               cur_x, wbt_l, Hb, bncoef, N_NODES);
        }
        hipLaunchKernelGGL(k_agg, dim3(nb_node4), dim3(256), 0, stream,
                           Hb, rowptr, csr, csrd, dinv, b[layer], AGG);
        hipLaunchKernelGGL(k_bnstats, dim3(256), dim3(256), 0, stream, AGG, bnpart);
        hipLaunchKernelGGL(k_bnred, dim3(1), dim3(256), 0, stream,
                           bnpart, gm[layer], be[layer], bncoef);
    }

    hipLaunchKernelGGL(k_pool, dim3(N_GRAPHS), dim3(256), 0, stream,
                       AGG, batch, bncoef, pool, cnt);
    hipLaunchKernelGGL(k_mlp, dim3(N_GRAPHS), dim3(128), 0, stream,
                       pool, cnt, w1, b1, w2, b2, out);
}

// Round 10
// 429.090 us; speedup vs baseline: 1.6717x; 1.0466x over previous
//
#include <hip/hip_runtime.h>

#define N_NODES 50000
#define N_EDGES 800000
#define N_GRAPHS 256
#define HID 128
#define OUT_CH 10
#define BN_EPS 1e-5f

#define NBUCKET 98               // ceil(50000/512) buckets of 512 nodes
#define BCAP 10240               // per-bucket pair capacity (mean 8192, sd ~90)

// ---------------- workspace layout (4-byte element offsets) ----------------
#define OFF_H       0            // bf16 H: 50000*128 ushort -> 3.2M f32 slots
#define OFF_BNPART  3134464      // 256*256 f32 partials (overlaps dead Hb tail)
#define OFF_CSRD    3200000      // 800,000 f32 (dinv[src] per CSR slot)
#define OFF_WBT     4000000      // 3 * 128*136 ushort = 26,112 f32 slots
#define OFF_AGG     6400000      // 6,400,000 f32; bucketBuf overlaps (build only)
#define OFF_ROWPTR  12850000     // 50,001 i32
#define OFF_CSR     12950004     // 800,000 i32
#define OFF_DINV    13750004     // 50,000 f32
#define OFF_BNCOEF  13800004     // 256 f32 (scale[128], shift[128])
#define OFF_CNT     13833028     // 256 f32
#define OFF_BCNT    13833284     // NBUCKET i32
// bucketBuf: int2[NBUCKET*BCAP] at OFF_AGG (8 MB). Used only before the first
// k_agg writes AGG. BNPART: Hb rows 48976..50000, dead when bnstats runs.

#define WBT_PITCH 136            // ushorts per row (128 + 8 pad)

typedef __attribute__((ext_vector_type(8))) short bf16x8;
typedef __attribute__((ext_vector_type(4))) float f32x4;

__device__ __forceinline__ ushort f2bf(float f) {
    union { float f; unsigned u; } v; v.f = f;
    unsigned r = v.u + 0x7FFFu + ((v.u >> 16) & 1u);   // RNE
    return (ushort)(r >> 16);
}
__device__ __forceinline__ float bf2f(unsigned u16) {
    return __uint_as_float(u16 << 16);
}

// ---------------- zero bucket counters ----------------
__global__ void k_zero(int* bcnt) {
    int i = threadIdx.x;
    if (i < NBUCKET) bcnt[i] = 0;
}

// ---------------- bucket edges by dst>>9 (block-reserved append) ----------
__global__ __launch_bounds__(256) void k_bucket(const int* __restrict__ ei,
                                                int* __restrict__ bcnt,
                                                int2* __restrict__ buf) {
    __shared__ int histL[NBUCKET], baseL[NBUCKET], curL[NBUCKET];
    int t = threadIdx.x;
    if (t < NBUCKET) histL[t] = 0;
    __syncthreads();
    const int stride = gridDim.x * 256;
    for (int i = blockIdx.x * 256 + t; i < N_EDGES; i += stride)
        atomicAdd(&histL[ei[N_EDGES + i] >> 9], 1);
    __syncthreads();
    if (t < NBUCKET) {
        baseL[t] = atomicAdd(&bcnt[t], histL[t]);
        curL[t] = 0;
    }
    __syncthreads();
    for (int i = blockIdx.x * 256 + t; i < N_EDGES; i += stride) {
        int s = ei[i];
        int d = ei[N_EDGES + i];
        int b = d >> 9;
        int p = baseL[b] + atomicAdd(&curL[b], 1);
        if (p < BCAP) buf[b * BCAP + p] = make_int2(s, d);
    }
}

// ---------------- per-bucket CSR build: hist, scan, direct scatter ---------
// computes own edge-base from bcnt prefix; order canonicalized by k_sortseg.
__global__ __launch_bounds__(512) void k_csrbuild(const int2* __restrict__ buf,
                                                  const int* __restrict__ bcnt,
                                                  int* __restrict__ rowptr,
                                                  int* __restrict__ csr,
                                                  float* __restrict__ dinv) {
    __shared__ int off[512];
    __shared__ int cur[512];
    __shared__ int ebase_s;
    int b = blockIdx.x, t = threadIdx.x;
    int node0 = b << 9;
    int cnt = bcnt[b];
    const int2* mybuf = buf + b * BCAP;

    if (t == 0) {
        int acc = 0;
        for (int i = 0; i < b; ++i) acc += bcnt[i];
        ebase_s = acc;
        if (b == NBUCKET - 1) rowptr[N_NODES] = acc + cnt;
    }
    off[t] = 0;
    __syncthreads();
    int ebase = ebase_s;
    for (int e = t; e < cnt; e += 512)
        atomicAdd(&off[mybuf[e].y - node0], 1);
    __syncthreads();
    int mydeg = off[t];
    // inclusive block scan (Hillis-Steele)
    for (int o = 1; o < 512; o <<= 1) {
        int x = (t >= o) ? off[t - o] : 0;
        __syncthreads();
        off[t] += x;
        __syncthreads();
    }
    int inc = off[t];
    cur[t] = ebase + inc - mydeg;
    int node = node0 + t;
    if (node < N_NODES) {
        rowptr[node] = ebase + inc - mydeg;
        dinv[node] = rsqrtf((float)(mydeg + 1));
    }
    __syncthreads();
    for (int e = t; e < cnt; e += 512) {
        int2 pr = mybuf[e];
        int p = atomicAdd(&cur[pr.y - node0], 1);
        csr[p] = pr.x;
    }
}

// ---------------- canonicalize: sort each segment ascending, fill csrd -----
// one wave per node; 64-lane bitonic sort via shfl_xor (register-only).
__global__ __launch_bounds__(256) void k_sortseg(const int* __restrict__ rowptr,
                                                 int* __restrict__ csr,
                                                 const float* __restrict__ dinv,
                                                 float* __restrict__ csrd) {
    int wave = threadIdx.x >> 6, lane = threadIdx.x & 63;
    int v = blockIdx.x * 4 + wave;
    if (v >= N_NODES) return;
    int e0 = rowptr[v], deg = rowptr[v + 1] - e0;
    if (deg <= 64) {
        int val = (lane < deg) ? csr[e0 + lane] : 0x7FFFFFFF;
#pragma unroll
        for (int k = 2; k <= 64; k <<= 1)
#pragma unroll
            for (int j = k >> 1; j > 0; j >>= 1) {
                int other = __shfl_xor(val, j);
                bool up = ((lane & k) == 0);
                bool lower = ((lane & j) == 0);
                int mn = min(val, other), mx = max(val, other);
                val = (up == lower) ? mn : mx;
            }
        if (lane < deg) {
            csr[e0 + lane] = val;
            csrd[e0 + lane] = dinv[val];
        }
    } else {
        if (lane == 0) {
            for (int i = e0 + 1; i < e0 + deg; ++i) {
                int key = csr[i];
                int j = i - 1;
                while (j >= e0 && csr[j] > key) { csr[j + 1] = csr[j]; --j; }
                csr[j + 1] = key;
            }
        }
        for (int e = e0 + lane; e < e0 + deg; e += 64) csrd[e] = dinv[csr[e]];
    }
}

// ---------------- W prep (all 3 layers): Wbt[c][k] = bf16(W[k][c]) ---------
__global__ void k_wprep3(const float* __restrict__ W0, const float* __restrict__ W1,
                         const float* __restrict__ W2, ushort* __restrict__ Wbt) {
    int i = blockIdx.x * 256 + threadIdx.x;   // 0..49151
    if (i < 3 * 16384) {
        int layer = i / 16384, r = i - layer * 16384;
        const float* W = (layer == 0) ? W0 : (layer == 1) ? W1 : W2;
        int k = r >> 7, c = r & 127;
        Wbt[layer * 128 * WBT_PITCH + c * WBT_PITCH + k] = f2bf(W[r]);
    }
}

// ---------------- MFMA GEMM: Hb[n,128](bf16) = f(X)[n,128] @ W -------------
template <int BN>
__global__ __launch_bounds__(256) void k_gemm(const float* __restrict__ X,
                                              const ushort* __restrict__ Wbt,
                                              ushort* __restrict__ Hb,
                                              const float* __restrict__ coef,
                                              int nrows) {
    __shared__ __align__(16) ushort Wt[128 * WBT_PITCH];
    int t = threadIdx.x;
    for (int i = t; i < 2176; i += 256)
        ((uint4*)Wt)[i] = ((const uint4*)Wbt)[i];
    __syncthreads();

    int wv = t >> 6, l = t & 63;
    int m = l & 15;
    int kg = l >> 4;
    int row = blockIdx.x * 64 + wv * 16 + m;
    bool valid = row < nrows;
    const float* xr = X + (long)row * 128;

    f32x4 acc[8];
#pragma unroll
    for (int n = 0; n < 8; ++n) acc[n] = (f32x4){0.f, 0.f, 0.f, 0.f};

#pragma unroll
    for (int t4 = 0; t4 < 4; ++t4) {
        int k0 = t4 * 32 + kg * 8;
        float xv[8];
        if (valid) {
            float4 u0 = *(const float4*)(xr + k0);
            float4 u1 = *(const float4*)(xr + k0 + 4);
            if (BN) {
                float4 s0 = *(const float4*)(coef + k0);
                float4 s1 = *(const float4*)(coef + k0 + 4);
                float4 h0 = *(const float4*)(coef + 128 + k0);
                float4 h1 = *(const float4*)(coef + 128 + k0 + 4);
                u0.x = fmaxf(u0.x * s0.x + h0.x, 0.f);
                u0.y = fmaxf(u0.y * s0.y + h0.y, 0.f);
                u0.z = fmaxf(u0.z * s0.z + h0.z, 0.f);
                u0.w = fmaxf(u0.w * s0.w + h0.w, 0.f);
                u1.x = fmaxf(u1.x * s1.x + h1.x, 0.f);
                u1.y = fmaxf(u1.y * s1.y + h1.y, 0.f);
                u1.z = fmaxf(u1.z * s1.z + h1.z, 0.f);
                u1.w = fmaxf(u1.w * s1.w + h1.w, 0.f);
            }
            xv[0] = u0.x; xv[1] = u0.y; xv[2] = u0.z; xv[3] = u0.w;
            xv[4] = u1.x; xv[5] = u1.y; xv[6] = u1.z; xv[7] = u1.w;
        } else {
#pragma unroll
            for (int j = 0; j < 8; ++j) xv[j] = 0.f;
        }
        union { ushort u[8]; bf16x8 v; } A;
#pragma unroll
        for (int j = 0; j < 8; ++j) A.u[j] = f2bf(xv[j]);

#pragma unroll
        for (int n = 0; n < 8; ++n) {
            bf16x8 b = *(const bf16x8*)(&Wt[(n * 16 + m) * WBT_PITCH + k0]);
            acc[n] = __builtin_amdgcn_mfma_f32_16x16x32_bf16(A.v, b, acc[n], 0, 0, 0);
        }
    }

    int srow0 = blockIdx.x * 64 + wv * 16 + kg * 4;
#pragma unroll
    for (int n = 0; n < 8; ++n)
#pragma unroll
        for (int r = 0; r < 4; ++r) {
            int rr = srow0 + r;
            if (rr < nrows) Hb[(long)rr * 128 + n * 16 + m] = f2bf(acc[n][r]);
        }
}

// ---------------- aggregation: quarter-wave per edge (16 lanes x 8 ch) -----
// 4 edges per issue round, 4-deep unroll -> 16 uint4 gathers in flight.
__global__ __launch_bounds__(256) void k_agg(const ushort* __restrict__ Hb,
                                             const int* __restrict__ rowptr,
                                             const int* __restrict__ csr,
                                             const float* __restrict__ csrd,
                                             const float* __restrict__ dinv,
                                             const float* __restrict__ bias,
                                             float* __restrict__ OUT) {
    int wave = threadIdx.x >> 6, lane = threadIdx.x & 63;
    int v = blockIdx.x * 4 + wave;
    if (v >= N_NODES) return;
    int q = lane >> 4, ql = lane & 15;
    int c = ql * 8;
    float dv = dinv[v];
    int e0 = rowptr[v];
    int deg = rowptr[v + 1] - e0;
    float a0 = 0.f, a1 = 0.f, a2 = 0.f, a3 = 0.f;
    float a4 = 0.f, a5 = 0.f, a6 = 0.f, a7 = 0.f;

    for (int base = 0; base < deg; base += 64) {
        int mye = base + lane;
        int idx = 0; float dvi = 0.f;
        if (mye < deg) { idx = csr[e0 + mye]; dvi = csrd[e0 + mye]; }
        int n = min(64, deg - base);
        int P = (n + 3) >> 2;
        int p = 0;
#define EDGE(pp) { \
        int sl = 4 * (pp) + q; \
        int s = __shfl(idx, sl); \
        float cf = __shfl(dvi, sl) * dv; \
        uint4 qv = *(const uint4*)(Hb + (long)s * 128 + c); \
        a0 += cf * bf2f(qv.x & 0xFFFFu); \
        a1 += cf * bf2f(qv.x >> 16); \
        a2 += cf * bf2f(qv.y & 0xFFFFu); \
        a3 += cf * bf2f(qv.y >> 16); \
        a4 += cf * bf2f(qv.z & 0xFFFFu); \
        a5 += cf * bf2f(qv.z >> 16); \
        a6 += cf * bf2f(qv.w & 0xFFFFu); \
        a7 += cf * bf2f(qv.w >> 16); }
        for (; p + 4 <= P; p += 4) { EDGE(p) EDGE(p + 1) EDGE(p + 2) EDGE(p + 3) }
        for (; p < P; ++p) { EDGE(p) }
#undef EDGE
    }
    // reduce across the 4 quarters (lanes with same ql)
    a0 += __shfl_xor(a0, 16); a0 += __shfl_xor(a0, 32);
    a1 += __shfl_xor(a1, 16); a1 += __shfl_xor(a1, 32);
    a2 += __shfl_xor(a2, 16); a2 += __shfl_xor(a2, 32);
    a3 += __shfl_xor(a3, 16); a3 += __shfl_xor(a3, 32);
    a4 += __shfl_xor(a4, 16); a4 += __shfl_xor(a4, 32);
    a5 += __shfl_xor(a5, 16); a5 += __shfl_xor(a5, 32);
    a6 += __shfl_xor(a6, 16); a6 += __shfl_xor(a6, 32);
    a7 += __shfl_xor(a7, 16); a7 += __shfl_xor(a7, 32);
    if (q == 0) {
        uint4 qv = *(const uint4*)(Hb + (long)v * 128 + c);
        float cs = dv * dv;
        float4 b0 = *(const float4*)(bias + c);
        float4 b1 = *(const float4*)(bias + c + 4);
        float4 o0, o1;
        o0.x = a0 + cs * bf2f(qv.x & 0xFFFFu) + b0.x;
        o0.y = a1 + cs * bf2f(qv.x >> 16) + b0.y;
        o0.z = a2 + cs * bf2f(qv.y & 0xFFFFu) + b0.z;
        o0.w = a3 + cs * bf2f(qv.y >> 16) + b0.w;
        o1.x = a4 + cs * bf2f(qv.z & 0xFFFFu) + b1.x;
        o1.y = a5 + cs * bf2f(qv.z >> 16) + b1.y;
        o1.z = a6 + cs * bf2f(qv.w & 0xFFFFu) + b1.z;
        o1.w = a7 + cs * bf2f(qv.w >> 16) + b1.w;
        *(float4*)(OUT + (long)v * 128 + c) = o0;
        *(float4*)(OUT + (long)v * 128 + c + 4) = o1;
    }
}

// ---------------- BN stats phase 1: per-block partials (no atomics) --------
__global__ __launch_bounds__(256) void k_bnstats(const float* __restrict__ X,
                                                 float* __restrict__ part) {
    int ch = threadIdx.x & 127;
    int half = threadIdx.x >> 7;
    float s = 0.f, q = 0.f;
    for (int v = blockIdx.x * 2 + half; v < N_NODES; v += 512) {
        float x = X[(long)v * 128 + ch];
        s += x;
        q += x * x;
    }
    __shared__ float sh[256];
    sh[threadIdx.x] = s;
    __syncthreads();
    float s2 = (half == 0) ? s + sh[threadIdx.x + 128] : 0.f;
    __syncthreads();
    sh[threadIdx.x] = q;
    __syncthreads();
    if (half == 0) {
        float q2 = q + sh[threadIdx.x + 128];
        part[blockIdx.x * 256 + ch] = s2;
        part[blockIdx.x * 256 + 128 + ch] = q2;
    }
}

// ---------------- BN stats phase 2: fixed-order reduce + coef --------------
__global__ void k_bnred(const float* __restrict__ part, const float* __restrict__ g,
                        const float* __restrict__ be, float* __restrict__ coef) {
    int t = threadIdx.x;
    int ch = t & 127, stat = t >> 7;
    float acc = 0.f;
    for (int b = 0; b < 256; ++b) acc += part[b * 256 + stat * 128 + ch];
    __shared__ float sh[256];
    sh[t] = acc;
    __syncthreads();
    if (stat == 0) {
        float inv_n = 1.0f / (float)N_NODES;
        float mean = acc * inv_n;
        float var = sh[128 + ch] * inv_n - mean * mean;
        float sc = g[ch] * rsqrtf(var + BN_EPS);
        coef[ch] = sc;
        coef[128 + ch] = be[ch] - mean * sc;
    }
}

// ---------------- pooling + MLP fused: one block per graph -----------------
__global__ __launch_bounds__(256) void k_poolmlp(const float* __restrict__ X,
                                                 const int* __restrict__ batch,
                                                 const float* __restrict__ coef,
                                                 const float* __restrict__ w1,
                                                 const float* __restrict__ b1,
                                                 const float* __restrict__ w2,
                                                 const float* __restrict__ b2,
                                                 float* __restrict__ out) {
    __shared__ int bounds[2];
    __shared__ float red[256];
    __shared__ float h[256];
    __shared__ float h1[128];
    int g = blockIdx.x, t = threadIdx.x;
    if (t < 2) {
        int target = g + t;
        int lo = 0, hi = N_NODES;
        while (lo < hi) {
            int mid = (lo + hi) >> 1;
            if (batch[mid] < target) lo = mid + 1; else hi = mid;
        }
        bounds[t] = lo;
    }
    __syncthreads();
    int start = bounds[0], end = bounds[1];
    int ch = t & 127, half = t >> 7;
    float sc = coef[ch], shv = coef[128 + ch];
    float acc = 0.f;
    for (int v = start + half; v < end; v += 2)
        acc += fmaxf(X[(long)v * 128 + ch] * sc + shv, 0.f);
    red[t] = acc;
    __syncthreads();
    if (half == 0) {
        float s = red[ch] + red[128 + ch];
        h[128 + ch] = s;                                   // sum
        h[ch] = s / fmaxf((float)(end - start), 1.0f);     // mean
    }
    __syncthreads();
    if (t < 128) {
        float a = b1[t];
#pragma unroll 4
        for (int i = 0; i < 256; ++i) a += h[i] * w1[i * 128 + t];
        h1[t] = fmaxf(a, 0.f);
    }
    __syncthreads();
    if (t < OUT_CH) {
        float o = b2[t];
#pragma unroll 4
        for (int j = 0; j < 128; ++j) o += h1[j] * w2[j * OUT_CH + t];
        out[g * OUT_CH + t] = o;
    }
}

extern "C" void kernel_launch(void* const* d_in, const int* in_sizes, int n_in,
                              void* d_out, int out_size, void* d_ws, size_t ws_size,
                              hipStream_t stream) {
    const float* x = (const float*)d_in[0];
    const int* ei = (const int*)d_in[1];
    const int* batch = (const int*)d_in[2];
    const float* W[3] = {(const float*)d_in[3], (const float*)d_in[7], (const float*)d_in[11]};
    const float* b[3] = {(const float*)d_in[4], (const float*)d_in[8], (const float*)d_in[12]};
    const float* gm[3] = {(const float*)d_in[5], (const float*)d_in[9], (const float*)d_in[13]};
    const float* be[3] = {(const float*)d_in[6], (const float*)d_in[10], (const float*)d_in[14]};
    const float* w1 = (const float*)d_in[15];
    const float* b1 = (const float*)d_in[16];
    const float* w2 = (const float*)d_in[17];
    const float* b2 = (const float*)d_in[18];
    float* out = (float*)d_out;

    float* ws = (float*)d_ws;
    ushort* Hb = (ushort*)(ws + OFF_H);
    float* bnpart = ws + OFF_BNPART;
    float* csrd = ws + OFF_CSRD;
    ushort* Wbt = (ushort*)(ws + OFF_WBT);
    float* AGG = ws + OFF_AGG;
    int2* bucketBuf = (int2*)(ws + OFF_AGG);
    int* rowptr = (int*)(ws + OFF_ROWPTR);
    int* csr = (int*)(ws + OFF_CSR);
    float* dinv = ws + OFF_DINV;
    float* bncoef = ws + OFF_BNCOEF;
    int* bcnt = (int*)(ws + OFF_BCNT);

    const int nb_node4 = (N_NODES + 3) / 4;     // 12500

    hipLaunchKernelGGL(k_zero, dim3(1), dim3(128), 0, stream, bcnt);
    hipLaunchKernelGGL(k_bucket, dim3(392), dim3(256), 0, stream, ei, bcnt, bucketBuf);
    hipLaunchKernelGGL(k_csrbuild, dim3(NBUCKET), dim3(512), 0, stream,
                       bucketBuf, bcnt, rowptr, csr, dinv);
    hipLaunchKernelGGL(k_sortseg, dim3(nb_node4), dim3(256), 0, stream,
                       rowptr, csr, dinv, csrd);
    hipLaunchKernelGGL(k_wprep3, dim3(192), dim3(256), 0, stream,
                       W[0], W[1], W[2], Wbt);

    const int gemm_blocks = (N_NODES + 63) / 64;  // 782
    for (int layer = 0; layer < 3; ++layer) {
        const float* cur_x = (layer == 0) ? x : AGG;
        const ushort* wbt_l = Wbt + layer * 128 * WBT_PITCH;
        if (layer == 0) {
            hipLaunchKernelGGL(k_gemm<0>, dim3(gemm_blocks), dim3(256), 0, stream,
                               cur_x, wbt_l, Hb, (const float*)nullptr, N_NODES);
        } else {
            hipLaunchKernelGGL(k_gemm<1>, dim3(gemm_blocks), dim3(256), 0, stream,
                               cur_x, wbt_l, Hb, bncoef, N_NODES);
        }
        hipLaunchKernelGGL(k_agg, dim3(nb_node4), dim3(256), 0, stream,
                           Hb, rowptr, csr, csrd, dinv, b[layer], AGG);
        hipLaunchKernelGGL(k_bnstats, dim3(256), dim3(256), 0, stream, AGG, bnpart);
        hipLaunchKernelGGL(k_bnred, dim3(1), dim3(256), 0, stream,
                           bnpart, gm[layer], be[layer], bncoef);
    }

    hipLaunchKernelGGL(k_poolmlp, dim3(N_GRAPHS), dim3(256), 0, stream,
                       AGG, batch, bncoef, w1, b1, w2, b2, out);
}

// Round 11
// 407.795 us; speedup vs baseline: 1.7590x; 1.0522x over previous
//
#include <hip/hip_runtime.h>

#define N_NODES 50000
#define N_EDGES 800000
#define N_GRAPHS 256
#define HID 128
#define OUT_CH 10
#define BN_EPS 1e-5f

#define NBUCKET 98               // ceil(50000/512) buckets of 512 nodes
#define BCAP 10240               // per-bucket pair capacity (mean 8192, sd ~90)
#define BN_BLOCKS 1024           // k_bnstats grid

// ---------------- workspace layout (4-byte element offsets) ----------------
#define OFF_H       0            // bf16 H: 50000*128 ushort -> 3.2M f32 slots
#define OFF_BNPART  2937856      // 1024*256 f32 partials (dead Hb tail, rows 45904+)
#define OFF_CSRD    3200000      // 800,000 f32 (dinv[src] per CSR slot)
#define OFF_WBT     4000000      // 3 * 128*136 ushort = 26,112 f32 slots
#define OFF_AGG     6400000      // 6,400,000 f32; bucketBuf overlaps (build only)
#define OFF_ROWPTR  12850000     // 50,001 i32
#define OFF_CSR     12950004     // 800,000 i32
#define OFF_DINV    13750004     // 50,000 f32
#define OFF_BNCOEF  13800004     // 256 f32 (scale[128], shift[128])
#define OFF_BCNT    13833284     // NBUCKET i32
// bucketBuf: int2[NBUCKET*BCAP] at OFF_AGG (8 MB), used only pre-agg.
// BNPART: Hb rows 45904..50000 region, dead once k_agg consumed Hb.

#define WBT_PITCH 136            // ushorts per row (128 + 8 pad)

typedef __attribute__((ext_vector_type(8))) short bf16x8;
typedef __attribute__((ext_vector_type(4))) float f32x4;

__device__ __forceinline__ ushort f2bf(float f) {
    union { float f; unsigned u; } v; v.f = f;
    unsigned r = v.u + 0x7FFFu + ((v.u >> 16) & 1u);   // RNE
    return (ushort)(r >> 16);
}
__device__ __forceinline__ float bf2f(unsigned u16) {
    return __uint_as_float(u16 << 16);
}

// ---------------- zero bucket counters ----------------
__global__ void k_zero(int* bcnt) {
    int i = threadIdx.x;
    if (i < NBUCKET) bcnt[i] = 0;
}

// ---------------- bucket edges by dst>>9 (block-reserved append) ----------
__global__ __launch_bounds__(256) void k_bucket(const int* __restrict__ ei,
                                                int* __restrict__ bcnt,
                                                int2* __restrict__ buf) {
    __shared__ int histL[NBUCKET], baseL[NBUCKET], curL[NBUCKET];
    int t = threadIdx.x;
    if (t < NBUCKET) histL[t] = 0;
    __syncthreads();
    const int stride = gridDim.x * 256;
    for (int i = blockIdx.x * 256 + t; i < N_EDGES; i += stride)
        atomicAdd(&histL[ei[N_EDGES + i] >> 9], 1);
    __syncthreads();
    if (t < NBUCKET) {
        baseL[t] = atomicAdd(&bcnt[t], histL[t]);
        curL[t] = 0;
    }
    __syncthreads();
    for (int i = blockIdx.x * 256 + t; i < N_EDGES; i += stride) {
        int s = ei[i];
        int d = ei[N_EDGES + i];
        int b = d >> 9;
        int p = baseL[b] + atomicAdd(&curL[b], 1);
        if (p < BCAP) buf[b * BCAP + p] = make_int2(s, d);
    }
}

// ---------------- per-bucket CSR build: hist, scan, direct scatter ---------
__global__ __launch_bounds__(512) void k_csrbuild(const int2* __restrict__ buf,
                                                  const int* __restrict__ bcnt,
                                                  int* __restrict__ rowptr,
                                                  int* __restrict__ csr,
                                                  float* __restrict__ dinv) {
    __shared__ int off[512];
    __shared__ int cur[512];
    __shared__ int ebase_s;
    int b = blockIdx.x, t = threadIdx.x;
    int node0 = b << 9;
    int cnt = bcnt[b];
    const int2* mybuf = buf + b * BCAP;

    if (t == 0) {
        int acc = 0;
        for (int i = 0; i < b; ++i) acc += bcnt[i];
        ebase_s = acc;
        if (b == NBUCKET - 1) rowptr[N_NODES] = acc + cnt;
    }
    off[t] = 0;
    __syncthreads();
    int ebase = ebase_s;
    for (int e = t; e < cnt; e += 512)
        atomicAdd(&off[mybuf[e].y - node0], 1);
    __syncthreads();
    int mydeg = off[t];
    for (int o = 1; o < 512; o <<= 1) {
        int x = (t >= o) ? off[t - o] : 0;
        __syncthreads();
        off[t] += x;
        __syncthreads();
    }
    int inc = off[t];
    cur[t] = ebase + inc - mydeg;
    int node = node0 + t;
    if (node < N_NODES) {
        rowptr[node] = ebase + inc - mydeg;
        dinv[node] = rsqrtf((float)(mydeg + 1));
    }
    __syncthreads();
    for (int e = t; e < cnt; e += 512) {
        int2 pr = mybuf[e];
        int p = atomicAdd(&cur[pr.y - node0], 1);
        csr[p] = pr.x;
    }
}

// ---------------- canonicalize: sort each segment ascending, fill csrd -----
__global__ __launch_bounds__(256) void k_sortseg(const int* __restrict__ rowptr,
                                                 int* __restrict__ csr,
                                                 const float* __restrict__ dinv,
                                                 float* __restrict__ csrd) {
    int wave = threadIdx.x >> 6, lane = threadIdx.x & 63;
    int v = blockIdx.x * 4 + wave;
    if (v >= N_NODES) return;
    int e0 = rowptr[v], deg = rowptr[v + 1] - e0;
    if (deg <= 64) {
        int val = (lane < deg) ? csr[e0 + lane] : 0x7FFFFFFF;
#pragma unroll
        for (int k = 2; k <= 64; k <<= 1)
#pragma unroll
            for (int j = k >> 1; j > 0; j >>= 1) {
                int other = __shfl_xor(val, j);
                bool up = ((lane & k) == 0);
                bool lower = ((lane & j) == 0);
                int mn = min(val, other), mx = max(val, other);
                val = (up == lower) ? mn : mx;
            }
        if (lane < deg) {
            csr[e0 + lane] = val;
            csrd[e0 + lane] = dinv[val];
        }
    } else {
        if (lane == 0) {
            for (int i = e0 + 1; i < e0 + deg; ++i) {
                int key = csr[i];
                int j = i - 1;
                while (j >= e0 && csr[j] > key) { csr[j + 1] = csr[j]; --j; }
                csr[j + 1] = key;
            }
        }
        for (int e = e0 + lane; e < e0 + deg; e += 64) csrd[e] = dinv[csr[e]];
    }
}

// ---------------- W prep (all 3 layers): Wbt[c][k] = bf16(W[k][c]) ---------
__global__ void k_wprep3(const float* __restrict__ W0, const float* __restrict__ W1,
                         const float* __restrict__ W2, ushort* __restrict__ Wbt) {
    int i = blockIdx.x * 256 + threadIdx.x;   // 0..49151
    if (i < 3 * 16384) {
        int layer = i / 16384, r = i - layer * 16384;
        const float* W = (layer == 0) ? W0 : (layer == 1) ? W1 : W2;
        int k = r >> 7, c = r & 127;
        Wbt[layer * 128 * WBT_PITCH + c * WBT_PITCH + k] = f2bf(W[r]);
    }
}

// ---------------- MFMA GEMM: Hb[n,128](bf16) = f(X)[n,128] @ W -------------
template <int BN>
__global__ __launch_bounds__(256) void k_gemm(const float* __restrict__ X,
                                              const ushort* __restrict__ Wbt,
                                              ushort* __restrict__ Hb,
                                              const float* __restrict__ coef,
                                              int nrows) {
    __shared__ __align__(16) ushort Wt[128 * WBT_PITCH];
    int t = threadIdx.x;
    for (int i = t; i < 2176; i += 256)
        ((uint4*)Wt)[i] = ((const uint4*)Wbt)[i];
    __syncthreads();

    int wv = t >> 6, l = t & 63;
    int m = l & 15;
    int kg = l >> 4;
    int row = blockIdx.x * 64 + wv * 16 + m;
    bool valid = row < nrows;
    const float* xr = X + (long)row * 128;

    f32x4 acc[8];
#pragma unroll
    for (int n = 0; n < 8; ++n) acc[n] = (f32x4){0.f, 0.f, 0.f, 0.f};

#pragma unroll
    for (int t4 = 0; t4 < 4; ++t4) {
        int k0 = t4 * 32 + kg * 8;
        float xv[8];
        if (valid) {
            float4 u0 = *(const float4*)(xr + k0);
            float4 u1 = *(const float4*)(xr + k0 + 4);
            if (BN) {
                float4 s0 = *(const float4*)(coef + k0);
                float4 s1 = *(const float4*)(coef + k0 + 4);
                float4 h0 = *(const float4*)(coef + 128 + k0);
                float4 h1 = *(const float4*)(coef + 128 + k0 + 4);
                u0.x = fmaxf(u0.x * s0.x + h0.x, 0.f);
                u0.y = fmaxf(u0.y * s0.y + h0.y, 0.f);
                u0.z = fmaxf(u0.z * s0.z + h0.z, 0.f);
                u0.w = fmaxf(u0.w * s0.w + h0.w, 0.f);
                u1.x = fmaxf(u1.x * s1.x + h1.x, 0.f);
                u1.y = fmaxf(u1.y * s1.y + h1.y, 0.f);
                u1.z = fmaxf(u1.z * s1.z + h1.z, 0.f);
                u1.w = fmaxf(u1.w * s1.w + h1.w, 0.f);
            }
            xv[0] = u0.x; xv[1] = u0.y; xv[2] = u0.z; xv[3] = u0.w;
            xv[4] = u1.x; xv[5] = u1.y; xv[6] = u1.z; xv[7] = u1.w;
        } else {
#pragma unroll
            for (int j = 0; j < 8; ++j) xv[j] = 0.f;
        }
        union { ushort u[8]; bf16x8 v; } A;
#pragma unroll
        for (int j = 0; j < 8; ++j) A.u[j] = f2bf(xv[j]);

#pragma unroll
        for (int n = 0; n < 8; ++n) {
            bf16x8 b = *(const bf16x8*)(&Wt[(n * 16 + m) * WBT_PITCH + k0]);
            acc[n] = __builtin_amdgcn_mfma_f32_16x16x32_bf16(A.v, b, acc[n], 0, 0, 0);
        }
    }

    int srow0 = blockIdx.x * 64 + wv * 16 + kg * 4;
#pragma unroll
    for (int n = 0; n < 8; ++n)
#pragma unroll
        for (int r = 0; r < 4; ++r) {
            int rr = srow0 + r;
            if (rr < nrows) Hb[(long)rr * 128 + n * 16 + m] = f2bf(acc[n][r]);
        }
}

// ---------------- aggregation: quarter-wave per edge (16 lanes x 8 ch) -----
__global__ __launch_bounds__(256) void k_agg(const ushort* __restrict__ Hb,
                                             const int* __restrict__ rowptr,
                                             const int* __restrict__ csr,
                                             const float* __restrict__ csrd,
                                             const float* __restrict__ dinv,
                                             const float* __restrict__ bias,
                                             float* __restrict__ OUT) {
    int wave = threadIdx.x >> 6, lane = threadIdx.x & 63;
    int v = blockIdx.x * 4 + wave;
    if (v >= N_NODES) return;
    int q = lane >> 4, ql = lane & 15;
    int c = ql * 8;
    float dv = dinv[v];
    int e0 = rowptr[v];
    int deg = rowptr[v + 1] - e0;
    float a0 = 0.f, a1 = 0.f, a2 = 0.f, a3 = 0.f;
    float a4 = 0.f, a5 = 0.f, a6 = 0.f, a7 = 0.f;

    for (int base = 0; base < deg; base += 64) {
        int mye = base + lane;
        int idx = 0; float dvi = 0.f;
        if (mye < deg) { idx = csr[e0 + mye]; dvi = csrd[e0 + mye]; }
        int n = min(64, deg - base);
        int P = (n + 3) >> 2;
        int p = 0;
#define EDGE(pp) { \
        int sl = 4 * (pp) + q; \
        int s = __shfl(idx, sl); \
        float cf = __shfl(dvi, sl) * dv; \
        uint4 qv = *(const uint4*)(Hb + (long)s * 128 + c); \
        a0 += cf * bf2f(qv.x & 0xFFFFu); \
        a1 += cf * bf2f(qv.x >> 16); \
        a2 += cf * bf2f(qv.y & 0xFFFFu); \
        a3 += cf * bf2f(qv.y >> 16); \
        a4 += cf * bf2f(qv.z & 0xFFFFu); \
        a5 += cf * bf2f(qv.z >> 16); \
        a6 += cf * bf2f(qv.w & 0xFFFFu); \
        a7 += cf * bf2f(qv.w >> 16); }
        for (; p + 4 <= P; p += 4) { EDGE(p) EDGE(p + 1) EDGE(p + 2) EDGE(p + 3) }
        for (; p < P; ++p) { EDGE(p) }
#undef EDGE
    }
    a0 += __shfl_xor(a0, 16); a0 += __shfl_xor(a0, 32);
    a1 += __shfl_xor(a1, 16); a1 += __shfl_xor(a1, 32);
    a2 += __shfl_xor(a2, 16); a2 += __shfl_xor(a2, 32);
    a3 += __shfl_xor(a3, 16); a3 += __shfl_xor(a3, 32);
    a4 += __shfl_xor(a4, 16); a4 += __shfl_xor(a4, 32);
    a5 += __shfl_xor(a5, 16); a5 += __shfl_xor(a5, 32);
    a6 += __shfl_xor(a6, 16); a6 += __shfl_xor(a6, 32);
    a7 += __shfl_xor(a7, 16); a7 += __shfl_xor(a7, 32);
    if (q == 0) {
        uint4 qv = *(const uint4*)(Hb + (long)v * 128 + c);
        float cs = dv * dv;
        float4 b0 = *(const float4*)(bias + c);
        float4 b1 = *(const float4*)(bias + c + 4);
        float4 o0, o1;
        o0.x = a0 + cs * bf2f(qv.x & 0xFFFFu) + b0.x;
        o0.y = a1 + cs * bf2f(qv.x >> 16) + b0.y;
        o0.z = a2 + cs * bf2f(qv.y & 0xFFFFu) + b0.z;
        o0.w = a3 + cs * bf2f(qv.y >> 16) + b0.w;
        o1.x = a4 + cs * bf2f(qv.z & 0xFFFFu) + b1.x;
        o1.y = a5 + cs * bf2f(qv.z >> 16) + b1.y;
        o1.z = a6 + cs * bf2f(qv.w & 0xFFFFu) + b1.z;
        o1.w = a7 + cs * bf2f(qv.w >> 16) + b1.w;
        *(float4*)(OUT + (long)v * 128 + c) = o0;
        *(float4*)(OUT + (long)v * 128 + c + 4) = o1;
    }
}

// ---------------- BN stats phase 1: per-block partials (no atomics) --------
__global__ __launch_bounds__(256) void k_bnstats(const float* __restrict__ X,
                                                 float* __restrict__ part) {
    int ch = threadIdx.x & 127;
    int half = threadIdx.x >> 7;
    float s = 0.f, q = 0.f;
    for (int v = blockIdx.x * 2 + half; v < N_NODES; v += BN_BLOCKS * 2) {
        float x = X[(long)v * 128 + ch];
        s += x;
        q += x * x;
    }
    __shared__ float sh[256];
    sh[threadIdx.x] = s;
    __syncthreads();
    float s2 = (half == 0) ? s + sh[threadIdx.x + 128] : 0.f;
    __syncthreads();
    sh[threadIdx.x] = q;
    __syncthreads();
    if (half == 0) {
        float q2 = q + sh[threadIdx.x + 128];
        part[blockIdx.x * 256 + ch] = s2;
        part[blockIdx.x * 256 + 128 + ch] = q2;
    }
}

// ---------------- BN stats phase 2: fixed-order reduce + coef --------------
__global__ void k_bnred(const float* __restrict__ part, const float* __restrict__ g,
                        const float* __restrict__ be, float* __restrict__ coef) {
    int t = threadIdx.x;
    int ch = t & 127, stat = t >> 7;
    float acc = 0.f;
    for (int b = 0; b < BN_BLOCKS; ++b) acc += part[b * 256 + stat * 128 + ch];
    __shared__ float sh[256];
    sh[t] = acc;
    __syncthreads();
    if (stat == 0) {
        float inv_n = 1.0f / (float)N_NODES;
        float mean = acc * inv_n;
        float var = sh[128 + ch] * inv_n - mean * mean;
        float sc = g[ch] * rsqrtf(var + BN_EPS);
        coef[ch] = sc;
        coef[128 + ch] = be[ch] - mean * sc;
    }
}

// ---------------- pooling + MLP fused: 1024 thr, 32-way node parallel ------
__global__ __launch_bounds__(1024) void k_poolmlp(const float* __restrict__ X,
                                                  const int* __restrict__ batch,
                                                  const float* __restrict__ coef,
                                                  const float* __restrict__ w1,
                                                  const float* __restrict__ b1,
                                                  const float* __restrict__ w2,
                                                  const float* __restrict__ b2,
                                                  float* __restrict__ out) {
    __shared__ int bounds[2];
    __shared__ float red[32][128];   // [way][ch], 16 KB
    __shared__ float h[256];
    __shared__ float h1[128];
    int g = blockIdx.x, t = threadIdx.x;
    if (t < 2) {
        int target = g + t;
        int lo = 0, hi = N_NODES;
        while (lo < hi) {
            int mid = (lo + hi) >> 1;
            if (batch[mid] < target) lo = mid + 1; else hi = mid;
        }
        bounds[t] = lo;
    }
    __syncthreads();
    int start = bounds[0], end = bounds[1];
    int way = t >> 5;              // 0..31
    int cg = (t & 31) << 2;        // channel group base 0,4,...,124
    float4 sc = *(const float4*)(coef + cg);
    float4 sh = *(const float4*)(coef + 128 + cg);
    float4 acc = make_float4(0.f, 0.f, 0.f, 0.f);
    for (int v = start + way; v < end; v += 32) {
        float4 xv = *(const float4*)(X + (long)v * 128 + cg);
        acc.x += fmaxf(xv.x * sc.x + sh.x, 0.f);
        acc.y += fmaxf(xv.y * sc.y + sh.y, 0.f);
        acc.z += fmaxf(xv.z * sc.z + sh.z, 0.f);
        acc.w += fmaxf(xv.w * sc.w + sh.w, 0.f);
    }
    *(float4*)(&red[way][cg]) = acc;
    __syncthreads();
    // fixed-order tree reduce over ways (deterministic)
#pragma unroll
    for (int off = 16; off > 0; off >>= 1) {
        if (way < off) {
            float4 a = *(float4*)(&red[way][cg]);
            float4 b = *(float4*)(&red[way + off][cg]);
            a.x += b.x; a.y += b.y; a.z += b.z; a.w += b.w;
            *(float4*)(&red[way][cg]) = a;
        }
        __syncthreads();
    }
    if (way == 0) {
        float4 s = *(float4*)(&red[0][cg]);
        float inv = 1.0f / fmaxf((float)(end - start), 1.0f);
        h[cg] = s.x * inv; h[cg + 1] = s.y * inv;
        h[cg + 2] = s.z * inv; h[cg + 3] = s.w * inv;     // mean
        h[128 + cg] = s.x; h[128 + cg + 1] = s.y;
        h[128 + cg + 2] = s.z; h[128 + cg + 3] = s.w;     // sum
    }
    __syncthreads();
    // lin1: 128 outputs x 8 K-ways of 32 MACs
    int o1 = t & 127, w8 = t >> 7;   // w8: 0..7
    float a = 0.f;
    int i0 = w8 * 32;
#pragma unroll 8
    for (int i = i0; i < i0 + 32; ++i) a += h[i] * w1[i * 128 + o1];
    red[w8][o1] = a;                 // reuse red as [8][128]
    __syncthreads();
    if (w8 == 0) {
        float s = b1[o1];
#pragma unroll
        for (int k = 0; k < 8; ++k) s += red[k][o1];
        h1[o1] = fmaxf(s, 0.f);
    }
    __syncthreads();
    if (t < OUT_CH) {
        float o = b2[t];
#pragma unroll 4
        for (int j = 0; j < 128; ++j) o += h1[j] * w2[j * OUT_CH + t];
        out[g * OUT_CH + t] = o;
    }
}

extern "C" void kernel_launch(void* const* d_in, const int* in_sizes, int n_in,
                              void* d_out, int out_size, void* d_ws, size_t ws_size,
                              hipStream_t stream) {
    const float* x = (const float*)d_in[0];
    const int* ei = (const int*)d_in[1];
    const int* batch = (const int*)d_in[2];
    const float* W[3] = {(const float*)d_in[3], (const float*)d_in[7], (const float*)d_in[11]};
    const float* b[3] = {(const float*)d_in[4], (const float*)d_in[8], (const float*)d_in[12]};
    const float* gm[3] = {(const float*)d_in[5], (const float*)d_in[9], (const float*)d_in[13]};
    const float* be[3] = {(const float*)d_in[6], (const float*)d_in[10], (const float*)d_in[14]};
    const float* w1 = (const float*)d_in[15];
    const float* b1 = (const float*)d_in[16];
    const float* w2 = (const float*)d_in[17];
    const float* b2 = (const float*)d_in[18];
    float* out = (float*)d_out;

    float* ws = (float*)d_ws;
    ushort* Hb = (ushort*)(ws + OFF_H);
    float* bnpart = ws + OFF_BNPART;
    float* csrd = ws + OFF_CSRD;
    ushort* Wbt = (ushort*)(ws + OFF_WBT);
    float* AGG = ws + OFF_AGG;
    int2* bucketBuf = (int2*)(ws + OFF_AGG);
    int* rowptr = (int*)(ws + OFF_ROWPTR);
    int* csr = (int*)(ws + OFF_CSR);
    float* dinv = ws + OFF_DINV;
    float* bncoef = ws + OFF_BNCOEF;
    int* bcnt = (int*)(ws + OFF_BCNT);

    const int nb_node4 = (N_NODES + 3) / 4;     // 12500

    hipLaunchKernelGGL(k_zero, dim3(1), dim3(128), 0, stream, bcnt);
    hipLaunchKernelGGL(k_bucket, dim3(392), dim3(256), 0, stream, ei, bcnt, bucketBuf);
    hipLaunchKernelGGL(k_csrbuild, dim3(NBUCKET), dim3(512), 0, stream,
                       bucketBuf, bcnt, rowptr, csr, dinv);
    hipLaunchKernelGGL(k_sortseg, dim3(nb_node4), dim3(256), 0, stream,
                       rowptr, csr, dinv, csrd);
    hipLaunchKernelGGL(k_wprep3, dim3(192), dim3(256), 0, stream,
                       W[0], W[1], W[2], Wbt);

    const int gemm_blocks = (N_NODES + 63) / 64;  // 782
    for (int layer = 0; layer < 3; ++layer) {
        const float* cur_x = (layer == 0) ? x : AGG;
        const ushort* wbt_l = Wbt + layer * 128 * WBT_PITCH;
        if (layer == 0) {
            hipLaunchKernelGGL(k_gemm<0>, dim3(gemm_blocks), dim3(256), 0, stream,
                               cur_x, wbt_l, Hb, (const float*)nullptr, N_NODES);
        } else {
            hipLaunchKernelGGL(k_gemm<1>, dim3(gemm_blocks), dim3(256), 0, stream,
                               cur_x, wbt_l, Hb, bncoef, N_NODES);
        }
        hipLaunchKernelGGL(k_agg, dim3(nb_node4), dim3(256), 0, stream,
                           Hb, rowptr, csr, csrd, dinv, b[layer], AGG);
        hipLaunchKernelGGL(k_bnstats, dim3(BN_BLOCKS), dim3(256), 0, stream, AGG, bnpart);
        hipLaunchKernelGGL(k_bnred, dim3(1), dim3(256), 0, stream,
                           bnpart, gm[layer], be[layer], bncoef);
    }

    hipLaunchKernelGGL(k_poolmlp, dim3(N_GRAPHS), dim3(1024), 0, stream,
                       AGG, batch, bncoef, w1, b1, w2, b2, out);
}